// Round 1
// 324.772 us; speedup vs baseline: 1.0669x; 1.0669x over previous
//
#include <hip/hip_runtime.h>

// ---------------------------------------------------------------------------
// GQA forward, fp32 I/O, bf16 MFMA compute.
// B=2 S=2048 D=2048 HQ=32 HKV=8 HD=64.
// 6 kernels: cvt4(x,Wq,Wk,Wv) -> QKV GEMM w/ fused RoPE epilogue (q scaled by
// 0.125*log2e so attn uses raw exp2) + XCD supertile swizzle -> V transpose ->
// flash attn (ROUND-5: 8 waves/block, 16 q-rows/wave, paired q-blocks, RS=72,
// exp2, scalar l, dbuf) -> cvt(Wo) -> O GEMM.
// ---------------------------------------------------------------------------

typedef __bf16 bf16x8 __attribute__((ext_vector_type(8)));
typedef __bf16 bf16x4 __attribute__((ext_vector_type(4)));
typedef float f32x4 __attribute__((ext_vector_type(4)));

__device__ inline f32x4 mfma16(bf16x8 a, bf16x8 b, f32x4 c) {
    return __builtin_amdgcn_mfma_f32_16x16x32_bf16(a, b, c, 0, 0, 0);
}

__device__ inline void gld16(const __bf16* g, __bf16* l) {
    __builtin_amdgcn_global_load_lds(
        (const __attribute__((address_space(1))) void*)g,
        (__attribute__((address_space(3))) void*)l, 16, 0, 0);
}

__device__ inline bf16x4 pk4(float a, float b, float c, float d) {
    bf16x4 r; r[0] = (__bf16)a; r[1] = (__bf16)b; r[2] = (__bf16)c; r[3] = (__bf16)d;
    return r;
}

// 1/sqrt(64) * log2(e): attn computes exp2(score) = exp(qk/8)
#define SCALE_Q 0.18033688011112042f
#define L2IF    0.4152410118609203f    // log2(10000)/32
#define INV2PI  0.15915494309189535f

// ---------------- fused fp32->bf16 for x, Wq, Wk, Wv ------------------------
__global__ void cvt4_kernel(const float* __restrict__ x,  const float* __restrict__ wq,
                            const float* __restrict__ wk, const float* __restrict__ wv,
                            __bf16* __restrict__ xb, __bf16* __restrict__ wqkvb)
{
    int i = blockIdx.x * blockDim.x + threadIdx.x;
    const float* src; __bf16* dst;
    if (i < 2097152)      { src = x  + (size_t)i * 4;  dst = xb + (size_t)i * 4; }
    else if (i < 3145728) { int j = i - 2097152; src = wq + (size_t)j * 4; dst = wqkvb + (size_t)j * 4; }
    else if (i < 3407872) { int j = i - 3145728; src = wk + (size_t)j * 4; dst = wqkvb + 4194304 + (size_t)j * 4; }
    else                  { int j = i - 3407872; src = wv + (size_t)j * 4; dst = wqkvb + 5242880 + (size_t)j * 4; }
    float4 f = *(const float4*)src;
    *(bf16x4*)dst = pk4(f.x, f.y, f.z, f.w);
}

__global__ void cvt_kernel(const float* __restrict__ in, __bf16* __restrict__ out, int n4)
{
    int i = blockIdx.x * blockDim.x + threadIdx.x;
    if (i >= n4) return;
    float4 f = ((const float4*)in)[i];
    ((bf16x4*)out)[i] = pk4(f.x, f.y, f.z, f.w);
}

// ---------------- GEMM: C[M,N] = A[M,K] * Bw[N,K]^T (bf16, fp32 acc) -------
// m97 structure + XCD supertile swizzle (requires gridDim.y == 32).
#define BK 32

template<bool ROPE, bool OUT_F32>
__global__ __launch_bounds__(256) void gemm_bt(
    const __bf16* __restrict__ A, const __bf16* __restrict__ Bw,
    void* __restrict__ Cv, int M, int N, int K)
{
    __shared__ __bf16 As[128 * BK];
    __shared__ __bf16 Bs[128 * BK];
    const int tid  = threadIdx.x;
    const int lane = tid & 63;
    const int w    = tid >> 6;
    const int lm   = lane & 15;
    const int quad = lane >> 4;
    const int wm   = (w >> 1) * 64;
    const int wn   = (w & 1) * 64;

    int bx, by;
    {
        int id  = blockIdx.x + gridDim.x * blockIdx.y;
        int xcd = id & 7;
        int j   = id >> 3;
        by = xcd * 4 + (j & 3);      // gy == 32
        bx = j >> 2;
    }
    const int m0 = by * 128;
    const int n0 = bx * 128;

    f32x4 acc[4][4];
    #pragma unroll
    for (int i = 0; i < 4; ++i)
        #pragma unroll
        for (int j = 0; j < 4; ++j)
            acc[i][j] = (f32x4){0.f, 0.f, 0.f, 0.f};

    const int srow = tid >> 2;
    const int sc8  = (tid & 3) * 8;
    const __bf16* gA0 = A  + (size_t)(m0 + srow) * K + sc8;
    const __bf16* gA1 = gA0 + (size_t)64 * K;
    const __bf16* gB0 = Bw + (size_t)(n0 + srow) * K + sc8;
    const __bf16* gB1 = gB0 + (size_t)64 * K;
    __bf16* lA0 = &As[srow * BK + sc8];
    __bf16* lA1 = &As[(srow + 64) * BK + sc8];
    __bf16* lB0 = &Bs[srow * BK + sc8];
    __bf16* lB1 = &Bs[(srow + 64) * BK + sc8];

    for (int k0 = 0; k0 < K; k0 += BK) {
        gld16(gA0 + k0, lA0);
        gld16(gA1 + k0, lA1);
        gld16(gB0 + k0, lB0);
        gld16(gB1 + k0, lB1);
        __syncthreads();

        bf16x8 af[4], bfr[4];
        #pragma unroll
        for (int i = 0; i < 4; ++i)
            af[i] = *(const bf16x8*)&As[(wm + i * 16 + lm) * BK + quad * 8];
        #pragma unroll
        for (int j = 0; j < 4; ++j)
            bfr[j] = *(const bf16x8*)&Bs[(wn + j * 16 + lm) * BK + quad * 8];
        #pragma unroll
        for (int i = 0; i < 4; ++i)
            #pragma unroll
            for (int j = 0; j < 4; ++j)
                acc[i][j] = mfma16(af[i], bfr[j], acc[i][j]);
        __syncthreads();
    }

    float sc = 1.0f;
    if (ROPE) {
        const int colbase = n0 + wn;            // 64-aligned; region-uniform per wave
        const int region  = (colbase < 2048) ? 0 : (colbase < 2560 ? 1 : 2);
        if (region < 2) {
            if (region == 0) sc = SCALE_Q;
            float invr[2];
            invr[0] = exp2f(-(float)lm        * L2IF) * INV2PI;
            invr[1] = exp2f(-(float)(16 + lm) * L2IF) * INV2PI;
            #pragma unroll
            for (int i = 0; i < 4; ++i)
                #pragma unroll
                for (int r = 0; r < 4; ++r) {
                    float t = (float)((m0 + wm + i * 16 + quad * 4 + r) & 2047);
                    #pragma unroll
                    for (int jp = 0; jp < 2; ++jp) {
                        float a = t * invr[jp];
                        a -= floorf(a);                       // revolutions in [0,1)
                        float cs = __builtin_amdgcn_cosf(a);
                        float sn = __builtin_amdgcn_sinf(a);
                        float x1 = acc[i][jp][r], x2 = acc[i][jp + 2][r];
                        acc[i][jp][r]     = x1 * cs - x2 * sn;
                        acc[i][jp + 2][r] = x2 * cs + x1 * sn;
                    }
                }
        }
    }

    #pragma unroll
    for (int i = 0; i < 4; ++i)
        #pragma unroll
        for (int j = 0; j < 4; ++j)
            #pragma unroll
            for (int r = 0; r < 4; ++r) {
                int row = m0 + wm + i * 16 + quad * 4 + r;
                int col = n0 + wn + j * 16 + lm;
                if (OUT_F32)
                    ((float*)Cv)[(size_t)row * N + col] = acc[i][j][r];
                else
                    ((__bf16*)Cv)[(size_t)row * N + col] = (__bf16)(acc[i][j][r] * sc);
            }
}

// ---------------- V transpose: [4096 tok][512 d] (stride 3072) -> [512][4096]
__global__ __launch_bounds__(256) void transpose_kernel(
    const __bf16* __restrict__ in, __bf16* __restrict__ out, int rowstride)
{
    __shared__ __bf16 T[64][72];
    const int t0 = blockIdx.x * 64;
    const int d0 = blockIdx.y * 64;
    const int r = threadIdx.x >> 2, c = (threadIdx.x & 3) * 16;
    *(int4*)&T[r][c]     = *(const int4*)(in + (size_t)(t0 + r) * rowstride + d0 + c);
    *(int4*)&T[r][c + 8] = *(const int4*)(in + (size_t)(t0 + r) * rowstride + d0 + c + 8);
    __syncthreads();
    bf16x8 o0, o1;
    #pragma unroll
    for (int i = 0; i < 8; ++i) { o0[i] = T[c + i][r]; o1[i] = T[c + 8 + i][r]; }
    *(bf16x8*)(out + (size_t)(d0 + r) * 4096 + t0 + c)     = o0;
    *(bf16x8*)(out + (size_t)(d0 + r) * 4096 + t0 + c + 8) = o1;
}

// ---------------- Flash attention (ROUND-5: 8 waves, 16 q-rows/wave) --------
// Transposed scores: St = mfma(A=K, B=Q) -> lane holds (kv=quad*4+r, q=lm).
// P packed to Pt[q][kv] with b64 writes; PV = mfma(A=Vt, B=Pt) -> O^T frags.
// Paired q-blocks (p, 15-p), K-tile 64, dbuf staging, 1 barrier/tile.
// 512 threads = 8 waves/block -> 16 waves/CU (4/SIMD) at 2 blocks/CU.
#define RS  72
#define PKS 72

__device__ inline void attn_tile(
    const bf16x8 (&qf)[2], f32x4 (&oacc)[4], float& l,
    int qbase, int k0, int w, int lm, int quad,
    const __bf16* Ks, const __bf16* Vs, __bf16* Ptw)
{
    f32x4 st[4];
    #pragma unroll
    for (int n = 0; n < 4; ++n)
        st[n] = (f32x4){0.f, 0.f, 0.f, 0.f};

    #pragma unroll
    for (int n = 0; n < 4; ++n) {
        bf16x8 kf0 = *(const bf16x8*)&Ks[(n * 16 + lm) * RS + quad * 8];
        bf16x8 kf1 = *(const bf16x8*)&Ks[(n * 16 + lm) * RS + 32 + quad * 8];
        st[n] = mfma16(kf0, qf[0], st[n]);
        st[n] = mfma16(kf1, qf[1], st[n]);
    }

    const int qi = qbase + w * 16 + lm;
    const bool any_mask = (k0 + 63 > qbase + w * 16);
    #pragma unroll
    for (int n = 0; n < 4; ++n) {
        const int kv0 = k0 + n * 16 + quad * 4;
        float e0, e1, e2, e3;
        if (any_mask) {
            e0 = (kv0     > qi) ? 0.f : __builtin_amdgcn_exp2f(st[n][0]);
            e1 = (kv0 + 1 > qi) ? 0.f : __builtin_amdgcn_exp2f(st[n][1]);
            e2 = (kv0 + 2 > qi) ? 0.f : __builtin_amdgcn_exp2f(st[n][2]);
            e3 = (kv0 + 3 > qi) ? 0.f : __builtin_amdgcn_exp2f(st[n][3]);
        } else {
            e0 = __builtin_amdgcn_exp2f(st[n][0]); e1 = __builtin_amdgcn_exp2f(st[n][1]);
            e2 = __builtin_amdgcn_exp2f(st[n][2]); e3 = __builtin_amdgcn_exp2f(st[n][3]);
        }
        l += (e0 + e1) + (e2 + e3);
        *(bf16x4*)&Ptw[lm * PKS + n * 16 + quad * 4] = pk4(e0, e1, e2, e3);
    }

    bf16x8 pf0 = *(const bf16x8*)&Ptw[lm * PKS + quad * 8];
    bf16x8 pf1 = *(const bf16x8*)&Ptw[lm * PKS + 32 + quad * 8];
    #pragma unroll
    for (int dt = 0; dt < 4; ++dt) {
        bf16x8 vf0 = *(const bf16x8*)&Vs[(dt * 16 + lm) * RS + quad * 8];
        bf16x8 vf1 = *(const bf16x8*)&Vs[(dt * 16 + lm) * RS + 32 + quad * 8];
        oacc[dt] = mfma16(vf0, pf0, oacc[dt]);
        oacc[dt] = mfma16(vf1, pf1, oacc[dt]);
    }
}

__device__ inline void attn_epilogue(
    f32x4 (&oacc)[4], float l,
    int qbase, int w, int lm, int quad, int b, int h, __bf16* o)
{
    float ls = l;
    ls += __shfl_xor(ls, 16);
    ls += __shfl_xor(ls, 32);
    float rinv = 1.0f / ls;
    const size_t rowbase = (size_t)(b * 2048 + qbase + w * 16 + lm) * 2048 + h * 64;
    #pragma unroll
    for (int dt = 0; dt < 4; ++dt) {
        *(bf16x4*)(o + rowbase + dt * 16 + quad * 4) =
            pk4(oacc[dt][0] * rinv, oacc[dt][1] * rinv,
                oacc[dt][2] * rinv, oacc[dt][3] * rinv);
    }
}

__global__ __launch_bounds__(512) void attn_kernel(
    const __bf16* __restrict__ qkv, const __bf16* __restrict__ vt,
    __bf16* __restrict__ o)
{
    __shared__ __bf16 Ks[2][64 * RS];
    __shared__ __bf16 Vs[2][64 * RS];
    __shared__ __bf16 Pt[8][16 * PKS];
    const int tid  = threadIdx.x;
    const int w    = tid >> 6;
    const int lane = tid & 63;
    const int lm   = lane & 15;
    const int quad = lane >> 4;
    const int p = blockIdx.x, h = blockIdx.y, b = blockIdx.z;
    const int kvh = h >> 2;
    const int qbA = p * 128, qbB = (15 - p) * 128;
    const int ntA = 2 * p + 2, ntB = 32 - 2 * p;
    __bf16* Ptw = &Pt[w][0];

    bf16x8 qfA[2], qfB[2];
    #pragma unroll
    for (int kh = 0; kh < 2; ++kh) {
        qfA[kh] = *(const bf16x8*)(qkv + (size_t)(b * 2048 + qbA + w * 16 + lm) * 3072
                                      + h * 64 + kh * 32 + quad * 8);
        qfB[kh] = *(const bf16x8*)(qkv + (size_t)(b * 2048 + qbB + w * 16 + lm) * 3072
                                      + h * 64 + kh * 32 + quad * 8);
    }

    f32x4 oA[4], oB[4];
    float lA = 0.f, lB = 0.f;
    #pragma unroll
    for (int j = 0; j < 4; ++j) {
        oA[j] = (f32x4){0.f, 0.f, 0.f, 0.f};
        oB[j] = (f32x4){0.f, 0.f, 0.f, 0.f};
    }

    const int srow = tid >> 3;
    const int scol = (tid & 7) * 8;
    const __bf16* kbase = qkv + (size_t)(b * 2048) * 3072 + 2048 + kvh * 64;
    const __bf16* vbase = vt  + (size_t)(kvh * 64 + srow) * 4096 + b * 2048;

    int4 kr0, vr0;
    kr0 = *(const int4*)(kbase + (size_t)srow * 3072 + scol);
    vr0 = *(const int4*)(vbase + scol);

    for (int kt = 0; kt < ntB; ++kt) {
        const int c = kt & 1;
        const int k0 = kt * 64;
        *(int4*)&Ks[c][srow * RS + scol] = kr0;
        *(int4*)&Vs[c][srow * RS + scol] = vr0;
        if (kt + 1 < ntB) {
            kr0 = *(const int4*)(kbase + (size_t)(k0 + 64 + srow) * 3072 + scol);
            vr0 = *(const int4*)(vbase + k0 + 64 + scol);
        }
        __syncthreads();
        attn_tile(qfB, oB, lB, qbB, k0, w, lm, quad, Ks[c], Vs[c], Ptw);
        if (kt < ntA)
            attn_tile(qfA, oA, lA, qbA, k0, w, lm, quad, Ks[c], Vs[c], Ptw);
    }

    attn_epilogue(oA, lA, qbA, w, lm, quad, b, h, o);
    attn_epilogue(oB, lB, qbB, w, lm, quad, b, h, o);
}

// ---------------------------------------------------------------------------
extern "C" void kernel_launch(void* const* d_in, const int* in_sizes, int n_in,
                              void* d_out, int out_size, void* d_ws, size_t ws_size,
                              hipStream_t stream)
{
    const float* x  = (const float*)d_in[0];
    const float* Wq = (const float*)d_in[1];
    const float* Wk = (const float*)d_in[2];
    const float* Wv = (const float*)d_in[3];
    const float* Wo = (const float*)d_in[4];

    const size_t Mi = 1u << 20;
    // d_out (32 MiB fp32) is scratch until the final GEMM writes it.
    char* ob = (char*)d_out;
    __bf16* xb    = (__bf16*)ob;              // 16 MiB  [4096][2048]
    __bf16* wqkvb = (__bf16*)(ob + 16 * Mi);  // 12 MiB  [3072][2048]
    __bf16* vt    = (__bf16*)(ob + 28 * Mi);  //  4 MiB  [512][4096]
    // d_ws (>= 40 MiB, proven)
    char* ws = (char*)d_ws;
    __bf16* qkvc = (__bf16*)ws;               // 24 MiB  [4096][3072]  Q|K|V
    __bf16* aws  = (__bf16*)(ws + 24 * Mi);   // 16 MiB  [4096][2048]
    __bf16* wob  = (__bf16*)ws;               //  8 MiB, reuses qkvc after attn

    dim3 blk(256);
    cvt4_kernel<<<14336, blk, 0, stream>>>(x, Wq, Wk, Wv, xb, wqkvb);
    gemm_bt<true, false><<<dim3(24, 32), blk, 0, stream>>>(xb, wqkvb, qkvc, 4096, 3072, 2048);
    transpose_kernel<<<dim3(64, 8), blk, 0, stream>>>(qkvc + 2560, vt, 3072);
    attn_kernel<<<dim3(8, 32, 2), dim3(512), 0, stream>>>(qkvc, vt, aws);
    cvt_kernel<<<4096, blk, 0, stream>>>(Wo, wob, 1048576);
    gemm_bt<false, true><<<dim3(16, 32), blk, 0, stream>>>(aws, wob, d_out, 4096, 2048, 2048);
}

// Round 3
// 315.111 us; speedup vs baseline: 1.0996x; 1.0307x over previous
//
#include <hip/hip_runtime.h>

// ---------------------------------------------------------------------------
// GQA forward, fp32 I/O, bf16 MFMA compute.
// B=2 S=2048 D=2048 HQ=32 HKV=8 HD=64.
// cvt4 -> QKV GEMM (ROUND-7: 256x256 8-wave 4-phase pipelined, counted vmcnt,
// XOR-swizzled LDS, setprio, explicit lgkmcnt(0) per template, fused RoPE) ->
// V transpose -> flash attn (8 waves, 16 q-rows/wave, exp2) -> cvt(Wo) ->
// O GEMM (m97 128x128 structure).
// ---------------------------------------------------------------------------

typedef __bf16 bf16x8 __attribute__((ext_vector_type(8)));
typedef __bf16 bf16x4 __attribute__((ext_vector_type(4)));
typedef float f32x4 __attribute__((ext_vector_type(4)));

__device__ inline f32x4 mfma16(bf16x8 a, bf16x8 b, f32x4 c) {
    return __builtin_amdgcn_mfma_f32_16x16x32_bf16(a, b, c, 0, 0, 0);
}

__device__ inline void gld16(const __bf16* g, __bf16* l) {
    __builtin_amdgcn_global_load_lds(
        (const __attribute__((address_space(1))) void*)g,
        (__attribute__((address_space(3))) void*)l, 16, 0, 0);
}

__device__ inline bf16x4 pk4(float a, float b, float c, float d) {
    bf16x4 r; r[0] = (__bf16)a; r[1] = (__bf16)b; r[2] = (__bf16)c; r[3] = (__bf16)d;
    return r;
}

// 1/sqrt(64) * log2(e): attn computes exp2(score) = exp(qk/8)
#define SCALE_Q 0.18033688011112042f
#define L2IF    0.4152410118609203f    // log2(10000)/32
#define INV2PI  0.15915494309189535f

// ---------------- fused fp32->bf16 for x, Wq, Wk, Wv ------------------------
__global__ void cvt4_kernel(const float* __restrict__ x,  const float* __restrict__ wq,
                            const float* __restrict__ wk, const float* __restrict__ wv,
                            __bf16* __restrict__ xb, __bf16* __restrict__ wqkvb)
{
    int i = blockIdx.x * blockDim.x + threadIdx.x;
    const float* src; __bf16* dst;
    if (i < 2097152)      { src = x  + (size_t)i * 4;  dst = xb + (size_t)i * 4; }
    else if (i < 3145728) { int j = i - 2097152; src = wq + (size_t)j * 4; dst = wqkvb + (size_t)j * 4; }
    else if (i < 3407872) { int j = i - 3145728; src = wk + (size_t)j * 4; dst = wqkvb + 4194304 + (size_t)j * 4; }
    else                  { int j = i - 3407872; src = wv + (size_t)j * 4; dst = wqkvb + 5242880 + (size_t)j * 4; }
    float4 f = *(const float4*)src;
    *(bf16x4*)dst = pk4(f.x, f.y, f.z, f.w);
}

__global__ void cvt_kernel(const float* __restrict__ in, __bf16* __restrict__ out, int n4)
{
    int i = blockIdx.x * blockDim.x + threadIdx.x;
    if (i >= n4) return;
    float4 f = ((const float4*)in)[i];
    ((bf16x4*)out)[i] = pk4(f.x, f.y, f.z, f.w);
}

// ---------------- 256x256 4-phase GEMM: C = A[M,K] * Bw[N,K]^T --------------
// 512 thr = 8 waves (2 Mx4 N), per-wave C = 128x64 = acc[8][4].
// K-tile 64, 4 phases/tile (C-quadrant each, 16 MFMA), dbuf LDS 128 KiB.
// Stage: 2 x gld16/phase (one 64-row round); vmcnt(5) once per tile.
// LDS XOR swizzle (slot ^= row&7): linear gld dest + pre-swizzled global col.
template<bool ROPE, bool OUT_F32>
__global__ __launch_bounds__(512, 2) void gemm256(
    const __bf16* __restrict__ A, const __bf16* __restrict__ Bw,
    void* __restrict__ Cv, int M, int N, int K)
{
    __shared__ __bf16 LA[2][16384];
    __shared__ __bf16 LB[2][16384];
    const int tid  = threadIdx.x;
    const int lane = tid & 63;
    const int w    = tid >> 6;
    const int lm   = lane & 15;
    const int quad = lane >> 4;
    const int wr   = w >> 2;     // 0..1
    const int wc   = w & 3;      // 0..3

    int bx, by;
    {
        int nwg = gridDim.x * gridDim.y;        // must be %8 == 0
        int id  = blockIdx.x + gridDim.x * blockIdx.y;
        int q   = nwg >> 3;
        int swz = (id & 7) * q + (id >> 3);
        by = swz / gridDim.x;
        bx = swz - by * gridDim.x;
    }
    const int m0 = by * 256;
    const int n0 = bx * 256;
    const int NT = K >> 6;

    // staging: thread covers (row = r0 + tid>>3, col slot XOR-permuted)
    const int srow = tid >> 3;
    const int scol = ((tid & 7) ^ (srow & 7)) * 8;   // pre-swizzled source col
    const int ldst = tid * 8;                        // linear LDS dest (elems)
    const __bf16* ga = A  + (size_t)(m0 + srow) * K + scol;
    const __bf16* gb = Bw + (size_t)(n0 + srow) * K + scol;

    auto STA = [&](int bf, int r, int u) {
        gld16(ga + (size_t)r * K + u * 64, &LA[bf][r * 64 + ldst]);
    };
    auto STB = [&](int bf, int r, int u) {
        gld16(gb + (size_t)r * K + u * 64, &LB[bf][r * 64 + ldst]);
    };

    f32x4 acc[8][4];
    #pragma unroll
    for (int i = 0; i < 8; ++i)
        #pragma unroll
        for (int j = 0; j < 4; ++j)
            acc[i][j] = (f32x4){0.f, 0.f, 0.f, 0.f};

    // fragment read offsets (elements); swizzled k-slices
    const int axo = (wr * 128 + lm) * 64;
    const int bxo = (wc * 64  + lm) * 64;
    const int ks0 = ((quad * 8)      ^ ((lm & 7) * 8));
    const int ks1 = ((32 + quad * 8) ^ ((lm & 7) * 8));

    // prologue: tile0 fully + tile1 early-5 rounds, drain to tile0
    STA(0, 0, 0); STA(0, 64, 0); STA(0, 128, 0); STA(0, 192, 0);
    STB(0, 0, 0); STB(0, 64, 0); STB(0, 128, 0); STB(0, 192, 0);
    STA(1, 0, 1); STA(1, 128, 1); STB(1, 0, 1); STA(1, 64, 1); STB(1, 64, 1);
    asm volatile("s_waitcnt vmcnt(5)" ::: "memory");
    __builtin_amdgcn_s_barrier();
    asm volatile("" ::: "memory");

    bf16x8 Af[4][2], Bf[4][2];
    for (int t = 0; t < NT; ++t) {
        const int b = t & 1;
        const __bf16* la = LA[b];
        const __bf16* lb = LB[b];
        // ---- P1: read A m0-3 (both k), B n0-1; MFMA quadrant (mL, nL)
        #pragma unroll
        for (int mi = 0; mi < 4; ++mi) {
            Af[mi][0] = *(const bf16x8*)(la + axo + mi * 1024 + ks0);
            Af[mi][1] = *(const bf16x8*)(la + axo + mi * 1024 + ks1);
        }
        #pragma unroll
        for (int ni = 0; ni < 2; ++ni) {
            Bf[ni][0] = *(const bf16x8*)(lb + bxo + ni * 1024 + ks0);
            Bf[ni][1] = *(const bf16x8*)(lb + bxo + ni * 1024 + ks1);
        }
        if (t + 1 < NT) { STA(b ^ 1, 192, t + 1); STB(b ^ 1, 128, t + 1); }
        __builtin_amdgcn_s_barrier();
        asm volatile("s_waitcnt lgkmcnt(0)" ::: "memory");
        __builtin_amdgcn_s_setprio(1);
        #pragma unroll
        for (int mi = 0; mi < 4; ++mi)
            #pragma unroll
            for (int ni = 0; ni < 2; ++ni) {
                acc[mi][ni] = mfma16(Af[mi][0], Bf[ni][0], acc[mi][ni]);
                acc[mi][ni] = mfma16(Af[mi][1], Bf[ni][1], acc[mi][ni]);
            }
        __builtin_amdgcn_s_setprio(0);
        __builtin_amdgcn_s_barrier();
        // ---- P2: read B n2-3; MFMA (mL, nH)
        #pragma unroll
        for (int ni = 2; ni < 4; ++ni) {
            Bf[ni][0] = *(const bf16x8*)(lb + bxo + ni * 1024 + ks0);
            Bf[ni][1] = *(const bf16x8*)(lb + bxo + ni * 1024 + ks1);
        }
        if (t + 1 < NT) STB(b ^ 1, 192, t + 1);
        if (t + 2 < NT) STA(b, 0, t + 2);
        __builtin_amdgcn_s_barrier();
        asm volatile("s_waitcnt lgkmcnt(0)" ::: "memory");
        __builtin_amdgcn_s_setprio(1);
        #pragma unroll
        for (int mi = 0; mi < 4; ++mi)
            #pragma unroll
            for (int ni = 2; ni < 4; ++ni) {
                acc[mi][ni] = mfma16(Af[mi][0], Bf[ni][0], acc[mi][ni]);
                acc[mi][ni] = mfma16(Af[mi][1], Bf[ni][1], acc[mi][ni]);
            }
        __builtin_amdgcn_s_setprio(0);
        __builtin_amdgcn_s_barrier();
        // ---- P3: read A m4-7; MFMA (mH, nL)
        #pragma unroll
        for (int mi = 0; mi < 4; ++mi) {
            Af[mi][0] = *(const bf16x8*)(la + axo + (mi + 4) * 1024 + ks0);
            Af[mi][1] = *(const bf16x8*)(la + axo + (mi + 4) * 1024 + ks1);
        }
        if (t + 2 < NT) { STA(b, 128, t + 2); STB(b, 0, t + 2); }
        __builtin_amdgcn_s_barrier();
        asm volatile("s_waitcnt lgkmcnt(0)" ::: "memory");
        __builtin_amdgcn_s_setprio(1);
        #pragma unroll
        for (int mi = 0; mi < 4; ++mi)
            #pragma unroll
            for (int ni = 0; ni < 2; ++ni) {
                acc[mi + 4][ni] = mfma16(Af[mi][0], Bf[ni][0], acc[mi + 4][ni]);
                acc[mi + 4][ni] = mfma16(Af[mi][1], Bf[ni][1], acc[mi + 4][ni]);
            }
        __builtin_amdgcn_s_setprio(0);
        __builtin_amdgcn_s_barrier();
        // ---- P4: MFMA (mH, nH); counted vmcnt; tile boundary
        if (t + 2 < NT) { STA(b, 64, t + 2); STB(b, 64, t + 2); }
        __builtin_amdgcn_s_barrier();
        __builtin_amdgcn_s_setprio(1);
        #pragma unroll
        for (int mi = 0; mi < 4; ++mi)
            #pragma unroll
            for (int ni = 2; ni < 4; ++ni) {
                acc[mi + 4][ni] = mfma16(Af[mi][0], Bf[ni][0], acc[mi + 4][ni]);
                acc[mi + 4][ni] = mfma16(Af[mi][1], Bf[ni][1], acc[mi + 4][ni]);
            }
        __builtin_amdgcn_s_setprio(0);
        if (t < NT - 2)       asm volatile("s_waitcnt vmcnt(5)" ::: "memory");
        else if (t == NT - 2) asm volatile("s_waitcnt vmcnt(0)" ::: "memory");
        __builtin_amdgcn_s_barrier();
        asm volatile("" ::: "memory");
    }

    float sc = 1.0f;
    if (ROPE) {
        const int colbase = n0 + wc * 64;       // 64-aligned, wave-uniform
        const int region  = (colbase < 2048) ? 0 : (colbase < 2560 ? 1 : 2);
        if (region < 2) {
            if (region == 0) sc = SCALE_Q;
            float invr[2];
            invr[0] = exp2f(-(float)lm        * L2IF) * INV2PI;
            invr[1] = exp2f(-(float)(16 + lm) * L2IF) * INV2PI;
            #pragma unroll
            for (int i = 0; i < 8; ++i)
                #pragma unroll
                for (int r = 0; r < 4; ++r) {
                    float tt = (float)((m0 + wr * 128 + i * 16 + quad * 4 + r) & 2047);
                    #pragma unroll
                    for (int jp = 0; jp < 2; ++jp) {
                        float aR = tt * invr[jp];
                        aR -= floorf(aR);                     // revolutions
                        float cs = __builtin_amdgcn_cosf(aR);
                        float sn = __builtin_amdgcn_sinf(aR);
                        float x1 = acc[i][jp][r], x2 = acc[i][jp + 2][r];
                        acc[i][jp][r]     = x1 * cs - x2 * sn;
                        acc[i][jp + 2][r] = x2 * cs + x1 * sn;
                    }
                }
        }
    }

    #pragma unroll
    for (int i = 0; i < 8; ++i)
        #pragma unroll
        for (int j = 0; j < 4; ++j)
            #pragma unroll
            for (int r = 0; r < 4; ++r) {
                int row = m0 + wr * 128 + i * 16 + quad * 4 + r;
                int col = n0 + wc * 64 + j * 16 + lm;
                if (OUT_F32)
                    ((float*)Cv)[(size_t)row * N + col] = acc[i][j][r];
                else
                    ((__bf16*)Cv)[(size_t)row * N + col] = (__bf16)(acc[i][j][r] * sc);
            }
}

// ---------------- GEMM: m97 128x128 structure (kept for O projection) -------
#define BK 32

template<bool ROPE, bool OUT_F32>
__global__ __launch_bounds__(256) void gemm_bt(
    const __bf16* __restrict__ A, const __bf16* __restrict__ Bw,
    void* __restrict__ Cv, int M, int N, int K)
{
    __shared__ __bf16 As[128 * BK];
    __shared__ __bf16 Bs[128 * BK];
    const int tid  = threadIdx.x;
    const int lane = tid & 63;
    const int w    = tid >> 6;
    const int lm   = lane & 15;
    const int quad = lane >> 4;
    const int wm   = (w >> 1) * 64;
    const int wn   = (w & 1) * 64;

    int bx, by;
    {
        int id  = blockIdx.x + gridDim.x * blockIdx.y;
        int xcd = id & 7;
        int j   = id >> 3;
        by = xcd * 4 + (j & 3);      // gy == 32
        bx = j >> 2;
    }
    const int m0 = by * 128;
    const int n0 = bx * 128;

    f32x4 acc[4][4];
    #pragma unroll
    for (int i = 0; i < 4; ++i)
        #pragma unroll
        for (int j = 0; j < 4; ++j)
            acc[i][j] = (f32x4){0.f, 0.f, 0.f, 0.f};

    const int srow = tid >> 2;
    const int sc8  = (tid & 3) * 8;
    const __bf16* gA0 = A  + (size_t)(m0 + srow) * K + sc8;
    const __bf16* gA1 = gA0 + (size_t)64 * K;
    const __bf16* gB0 = Bw + (size_t)(n0 + srow) * K + sc8;
    const __bf16* gB1 = gB0 + (size_t)64 * K;
    __bf16* lA0 = &As[srow * BK + sc8];
    __bf16* lA1 = &As[(srow + 64) * BK + sc8];
    __bf16* lB0 = &Bs[srow * BK + sc8];
    __bf16* lB1 = &Bs[(srow + 64) * BK + sc8];

    for (int k0 = 0; k0 < K; k0 += BK) {
        gld16(gA0 + k0, lA0);
        gld16(gA1 + k0, lA1);
        gld16(gB0 + k0, lB0);
        gld16(gB1 + k0, lB1);
        __syncthreads();

        bf16x8 af[4], bfr[4];
        #pragma unroll
        for (int i = 0; i < 4; ++i)
            af[i] = *(const bf16x8*)&As[(wm + i * 16 + lm) * BK + quad * 8];
        #pragma unroll
        for (int j = 0; j < 4; ++j)
            bfr[j] = *(const bf16x8*)&Bs[(wn + j * 16 + lm) * BK + quad * 8];
        #pragma unroll
        for (int i = 0; i < 4; ++i)
            #pragma unroll
            for (int j = 0; j < 4; ++j)
                acc[i][j] = mfma16(af[i], bfr[j], acc[i][j]);
        __syncthreads();
    }

    float sc = 1.0f;
    if (ROPE) {
        const int colbase = n0 + wn;
        const int region  = (colbase < 2048) ? 0 : (colbase < 2560 ? 1 : 2);
        if (region < 2) {
            if (region == 0) sc = SCALE_Q;
            float invr[2];
            invr[0] = exp2f(-(float)lm        * L2IF) * INV2PI;
            invr[1] = exp2f(-(float)(16 + lm) * L2IF) * INV2PI;
            #pragma unroll
            for (int i = 0; i < 4; ++i)
                #pragma unroll
                for (int r = 0; r < 4; ++r) {
                    float t = (float)((m0 + wm + i * 16 + quad * 4 + r) & 2047);
                    #pragma unroll
                    for (int jp = 0; jp < 2; ++jp) {
                        float a = t * invr[jp];
                        a -= floorf(a);
                        float cs = __builtin_amdgcn_cosf(a);
                        float sn = __builtin_amdgcn_sinf(a);
                        float x1 = acc[i][jp][r], x2 = acc[i][jp + 2][r];
                        acc[i][jp][r]     = x1 * cs - x2 * sn;
                        acc[i][jp + 2][r] = x2 * cs + x1 * sn;
                    }
                }
        }
    }

    #pragma unroll
    for (int i = 0; i < 4; ++i)
        #pragma unroll
        for (int j = 0; j < 4; ++j)
            #pragma unroll
            for (int r = 0; r < 4; ++r) {
                int row = m0 + wm + i * 16 + quad * 4 + r;
                int col = n0 + wn + j * 16 + lm;
                if (OUT_F32)
                    ((float*)Cv)[(size_t)row * N + col] = acc[i][j][r];
                else
                    ((__bf16*)Cv)[(size_t)row * N + col] = (__bf16)(acc[i][j][r] * sc);
            }
}

// ---------------- V transpose: [4096 tok][512 d] (stride 3072) -> [512][4096]
__global__ __launch_bounds__(256) void transpose_kernel(
    const __bf16* __restrict__ in, __bf16* __restrict__ out, int rowstride)
{
    __shared__ __bf16 T[64][72];
    const int t0 = blockIdx.x * 64;
    const int d0 = blockIdx.y * 64;
    const int r = threadIdx.x >> 2, c = (threadIdx.x & 3) * 16;
    *(int4*)&T[r][c]     = *(const int4*)(in + (size_t)(t0 + r) * rowstride + d0 + c);
    *(int4*)&T[r][c + 8] = *(const int4*)(in + (size_t)(t0 + r) * rowstride + d0 + c + 8);
    __syncthreads();
    bf16x8 o0, o1;
    #pragma unroll
    for (int i = 0; i < 8; ++i) { o0[i] = T[c + i][r]; o1[i] = T[c + 8 + i][r]; }
    *(bf16x8*)(out + (size_t)(d0 + r) * 4096 + t0 + c)     = o0;
    *(bf16x8*)(out + (size_t)(d0 + r) * 4096 + t0 + c + 8) = o1;
}

// ---------------- Flash attention (8 waves, 16 q-rows/wave) -----------------
#define RS  72
#define PKS 72

__device__ inline void attn_tile(
    const bf16x8 (&qf)[2], f32x4 (&oacc)[4], float& l,
    int qbase, int k0, int w, int lm, int quad,
    const __bf16* Ks, const __bf16* Vs, __bf16* Ptw)
{
    f32x4 st[4];
    #pragma unroll
    for (int n = 0; n < 4; ++n)
        st[n] = (f32x4){0.f, 0.f, 0.f, 0.f};

    #pragma unroll
    for (int n = 0; n < 4; ++n) {
        bf16x8 kf0 = *(const bf16x8*)&Ks[(n * 16 + lm) * RS + quad * 8];
        bf16x8 kf1 = *(const bf16x8*)&Ks[(n * 16 + lm) * RS + 32 + quad * 8];
        st[n] = mfma16(kf0, qf[0], st[n]);
        st[n] = mfma16(kf1, qf[1], st[n]);
    }

    const int qi = qbase + w * 16 + lm;
    const bool any_mask = (k0 + 63 > qbase + w * 16);
    #pragma unroll
    for (int n = 0; n < 4; ++n) {
        const int kv0 = k0 + n * 16 + quad * 4;
        float e0, e1, e2, e3;
        if (any_mask) {
            e0 = (kv0     > qi) ? 0.f : __builtin_amdgcn_exp2f(st[n][0]);
            e1 = (kv0 + 1 > qi) ? 0.f : __builtin_amdgcn_exp2f(st[n][1]);
            e2 = (kv0 + 2 > qi) ? 0.f : __builtin_amdgcn_exp2f(st[n][2]);
            e3 = (kv0 + 3 > qi) ? 0.f : __builtin_amdgcn_exp2f(st[n][3]);
        } else {
            e0 = __builtin_amdgcn_exp2f(st[n][0]); e1 = __builtin_amdgcn_exp2f(st[n][1]);
            e2 = __builtin_amdgcn_exp2f(st[n][2]); e3 = __builtin_amdgcn_exp2f(st[n][3]);
        }
        l += (e0 + e1) + (e2 + e3);
        *(bf16x4*)&Ptw[lm * PKS + n * 16 + quad * 4] = pk4(e0, e1, e2, e3);
    }

    bf16x8 pf0 = *(const bf16x8*)&Ptw[lm * PKS + quad * 8];
    bf16x8 pf1 = *(const bf16x8*)&Ptw[lm * PKS + 32 + quad * 8];
    #pragma unroll
    for (int dt = 0; dt < 4; ++dt) {
        bf16x8 vf0 = *(const bf16x8*)&Vs[(dt * 16 + lm) * RS + quad * 8];
        bf16x8 vf1 = *(const bf16x8*)&Vs[(dt * 16 + lm) * RS + 32 + quad * 8];
        oacc[dt] = mfma16(vf0, pf0, oacc[dt]);
        oacc[dt] = mfma16(vf1, pf1, oacc[dt]);
    }
}

__device__ inline void attn_epilogue(
    f32x4 (&oacc)[4], float l,
    int qbase, int w, int lm, int quad, int b, int h, __bf16* o)
{
    float ls = l;
    ls += __shfl_xor(ls, 16);
    ls += __shfl_xor(ls, 32);
    float rinv = 1.0f / ls;
    const size_t rowbase = (size_t)(b * 2048 + qbase + w * 16 + lm) * 2048 + h * 64;
    #pragma unroll
    for (int dt = 0; dt < 4; ++dt) {
        *(bf16x4*)(o + rowbase + dt * 16 + quad * 4) =
            pk4(oacc[dt][0] * rinv, oacc[dt][1] * rinv,
                oacc[dt][2] * rinv, oacc[dt][3] * rinv);
    }
}

__global__ __launch_bounds__(512) void attn_kernel(
    const __bf16* __restrict__ qkv, const __bf16* __restrict__ vt,
    __bf16* __restrict__ o)
{
    __shared__ __bf16 Ks[2][64 * RS];
    __shared__ __bf16 Vs[2][64 * RS];
    __shared__ __bf16 Pt[8][16 * PKS];
    const int tid  = threadIdx.x;
    const int w    = tid >> 6;
    const int lane = tid & 63;
    const int lm   = lane & 15;
    const int quad = lane >> 4;
    const int p = blockIdx.x, h = blockIdx.y, b = blockIdx.z;
    const int kvh = h >> 2;
    const int qbA = p * 128, qbB = (15 - p) * 128;
    const int ntA = 2 * p + 2, ntB = 32 - 2 * p;
    __bf16* Ptw = &Pt[w][0];

    bf16x8 qfA[2], qfB[2];
    #pragma unroll
    for (int kh = 0; kh < 2; ++kh) {
        qfA[kh] = *(const bf16x8*)(qkv + (size_t)(b * 2048 + qbA + w * 16 + lm) * 3072
                                      + h * 64 + kh * 32 + quad * 8);
        qfB[kh] = *(const bf16x8*)(qkv + (size_t)(b * 2048 + qbB + w * 16 + lm) * 3072
                                      + h * 64 + kh * 32 + quad * 8);
    }

    f32x4 oA[4], oB[4];
    float lA = 0.f, lB = 0.f;
    #pragma unroll
    for (int j = 0; j < 4; ++j) {
        oA[j] = (f32x4){0.f, 0.f, 0.f, 0.f};
        oB[j] = (f32x4){0.f, 0.f, 0.f, 0.f};
    }

    const int srow = tid >> 3;
    const int scol = (tid & 7) * 8;
    const __bf16* kbase = qkv + (size_t)(b * 2048) * 3072 + 2048 + kvh * 64;
    const __bf16* vbase = vt  + (size_t)(kvh * 64 + srow) * 4096 + b * 2048;

    int4 kr0, vr0;
    kr0 = *(const int4*)(kbase + (size_t)srow * 3072 + scol);
    vr0 = *(const int4*)(vbase + scol);

    for (int kt = 0; kt < ntB; ++kt) {
        const int c = kt & 1;
        const int k0 = kt * 64;
        *(int4*)&Ks[c][srow * RS + scol] = kr0;
        *(int4*)&Vs[c][srow * RS + scol] = vr0;
        if (kt + 1 < ntB) {
            kr0 = *(const int4*)(kbase + (size_t)(k0 + 64 + srow) * 3072 + scol);
            vr0 = *(const int4*)(vbase + k0 + 64 + scol);
        }
        __syncthreads();
        attn_tile(qfB, oB, lB, qbB, k0, w, lm, quad, Ks[c], Vs[c], Ptw);
        if (kt < ntA)
            attn_tile(qfA, oA, lA, qbA, k0, w, lm, quad, Ks[c], Vs[c], Ptw);
    }

    attn_epilogue(oA, lA, qbA, w, lm, quad, b, h, o);
    attn_epilogue(oB, lB, qbB, w, lm, quad, b, h, o);
}

// ---------------------------------------------------------------------------
extern "C" void kernel_launch(void* const* d_in, const int* in_sizes, int n_in,
                              void* d_out, int out_size, void* d_ws, size_t ws_size,
                              hipStream_t stream)
{
    const float* x  = (const float*)d_in[0];
    const float* Wq = (const float*)d_in[1];
    const float* Wk = (const float*)d_in[2];
    const float* Wv = (const float*)d_in[3];
    const float* Wo = (const float*)d_in[4];

    const size_t Mi = 1u << 20;
    // d_out (32 MiB fp32) is scratch until the final GEMM writes it.
    char* ob = (char*)d_out;
    __bf16* xb    = (__bf16*)ob;              // 16 MiB  [4096][2048]
    __bf16* wqkvb = (__bf16*)(ob + 16 * Mi);  // 12 MiB  [3072][2048]
    __bf16* vt    = (__bf16*)(ob + 28 * Mi);  //  4 MiB  [512][4096]
    // d_ws (>= 40 MiB, proven)
    char* ws = (char*)d_ws;
    __bf16* qkvc = (__bf16*)ws;               // 24 MiB  [4096][3072]  Q|K|V
    __bf16* aws  = (__bf16*)(ws + 24 * Mi);   // 16 MiB  [4096][2048]
    __bf16* wob  = (__bf16*)ws;               //  8 MiB, reuses qkvc after attn

    dim3 blk(256);
    cvt4_kernel<<<14336, blk, 0, stream>>>(x, Wq, Wk, Wv, xb, wqkvb);
    gemm256<true, false><<<dim3(12, 16), dim3(512), 0, stream>>>(xb, wqkvb, qkvc, 4096, 3072, 2048);
    transpose_kernel<<<dim3(64, 8), blk, 0, stream>>>(qkvc + 2560, vt, 3072);
    attn_kernel<<<dim3(8, 32, 2), dim3(512), 0, stream>>>(qkvc, vt, aws);
    cvt_kernel<<<4096, blk, 0, stream>>>(Wo, wob, 1048576);
    gemm_bt<false, true><<<dim3(16, 32), blk, 0, stream>>>(aws, wob, d_out, 4096, 2048, 2048);
}

// Round 4
// 310.725 us; speedup vs baseline: 1.1152x; 1.0141x over previous
//
#include <hip/hip_runtime.h>

// ---------------------------------------------------------------------------
// GQA forward, fp32 I/O, bf16 MFMA compute.
// B=2 S=2048 D=2048 HQ=32 HKV=8 HD=64.
// cvt4 -> QKV GEMM (256x256 8-wave 4-phase pipelined, counted vmcnt, XOR LDS
// swizzle, setprio, fused RoPE) -> V transpose -> flash attn (ROUND-8: fused
// paired-tile, shared K/V fragment reads, dbuf P, 8 waves, 16 q-rows/wave) ->
// cvt(Wo) -> O GEMM (m97 128x128 structure).
// ---------------------------------------------------------------------------

typedef __bf16 bf16x8 __attribute__((ext_vector_type(8)));
typedef __bf16 bf16x4 __attribute__((ext_vector_type(4)));
typedef float f32x4 __attribute__((ext_vector_type(4)));

__device__ inline f32x4 mfma16(bf16x8 a, bf16x8 b, f32x4 c) {
    return __builtin_amdgcn_mfma_f32_16x16x32_bf16(a, b, c, 0, 0, 0);
}

__device__ inline void gld16(const __bf16* g, __bf16* l) {
    __builtin_amdgcn_global_load_lds(
        (const __attribute__((address_space(1))) void*)g,
        (__attribute__((address_space(3))) void*)l, 16, 0, 0);
}

__device__ inline bf16x4 pk4(float a, float b, float c, float d) {
    bf16x4 r; r[0] = (__bf16)a; r[1] = (__bf16)b; r[2] = (__bf16)c; r[3] = (__bf16)d;
    return r;
}

// 1/sqrt(64) * log2(e): attn computes exp2(score) = exp(qk/8)
#define SCALE_Q 0.18033688011112042f
#define L2IF    0.4152410118609203f    // log2(10000)/32
#define INV2PI  0.15915494309189535f

// ---------------- fused fp32->bf16 for x, Wq, Wk, Wv ------------------------
__global__ void cvt4_kernel(const float* __restrict__ x,  const float* __restrict__ wq,
                            const float* __restrict__ wk, const float* __restrict__ wv,
                            __bf16* __restrict__ xb, __bf16* __restrict__ wqkvb)
{
    int i = blockIdx.x * blockDim.x + threadIdx.x;
    const float* src; __bf16* dst;
    if (i < 2097152)      { src = x  + (size_t)i * 4;  dst = xb + (size_t)i * 4; }
    else if (i < 3145728) { int j = i - 2097152; src = wq + (size_t)j * 4; dst = wqkvb + (size_t)j * 4; }
    else if (i < 3407872) { int j = i - 3145728; src = wk + (size_t)j * 4; dst = wqkvb + 4194304 + (size_t)j * 4; }
    else                  { int j = i - 3407872; src = wv + (size_t)j * 4; dst = wqkvb + 5242880 + (size_t)j * 4; }
    float4 f = *(const float4*)src;
    *(bf16x4*)dst = pk4(f.x, f.y, f.z, f.w);
}

__global__ void cvt_kernel(const float* __restrict__ in, __bf16* __restrict__ out, int n4)
{
    int i = blockIdx.x * blockDim.x + threadIdx.x;
    if (i >= n4) return;
    float4 f = ((const float4*)in)[i];
    ((bf16x4*)out)[i] = pk4(f.x, f.y, f.z, f.w);
}

// ---------------- 256x256 4-phase GEMM: C = A[M,K] * Bw[N,K]^T --------------
// 512 thr = 8 waves (2 Mx4 N), per-wave C = 128x64 = acc[8][4].
// K-tile 64, 4 phases/tile (C-quadrant each, 16 MFMA), dbuf LDS 128 KiB.
// Stage: 2 x gld16/phase (one 64-row round); vmcnt(5) once per tile.
// LDS XOR swizzle (slot ^= row&7): linear gld dest + pre-swizzled global col.
template<bool ROPE, bool OUT_F32>
__global__ __launch_bounds__(512, 2) void gemm256(
    const __bf16* __restrict__ A, const __bf16* __restrict__ Bw,
    void* __restrict__ Cv, int M, int N, int K)
{
    __shared__ __bf16 LA[2][16384];
    __shared__ __bf16 LB[2][16384];
    const int tid  = threadIdx.x;
    const int lane = tid & 63;
    const int w    = tid >> 6;
    const int lm   = lane & 15;
    const int quad = lane >> 4;
    const int wr   = w >> 2;     // 0..1
    const int wc   = w & 3;      // 0..3

    int bx, by;
    {
        int nwg = gridDim.x * gridDim.y;        // must be %8 == 0
        int id  = blockIdx.x + gridDim.x * blockIdx.y;
        int q   = nwg >> 3;
        int swz = (id & 7) * q + (id >> 3);
        by = swz / gridDim.x;
        bx = swz - by * gridDim.x;
    }
    const int m0 = by * 256;
    const int n0 = bx * 256;
    const int NT = K >> 6;

    // staging: thread covers (row = r0 + tid>>3, col slot XOR-permuted)
    const int srow = tid >> 3;
    const int scol = ((tid & 7) ^ (srow & 7)) * 8;   // pre-swizzled source col
    const int ldst = tid * 8;                        // linear LDS dest (elems)
    const __bf16* ga = A  + (size_t)(m0 + srow) * K + scol;
    const __bf16* gb = Bw + (size_t)(n0 + srow) * K + scol;

    auto STA = [&](int bf, int r, int u) {
        gld16(ga + (size_t)r * K + u * 64, &LA[bf][r * 64 + ldst]);
    };
    auto STB = [&](int bf, int r, int u) {
        gld16(gb + (size_t)r * K + u * 64, &LB[bf][r * 64 + ldst]);
    };

    f32x4 acc[8][4];
    #pragma unroll
    for (int i = 0; i < 8; ++i)
        #pragma unroll
        for (int j = 0; j < 4; ++j)
            acc[i][j] = (f32x4){0.f, 0.f, 0.f, 0.f};

    // fragment read offsets (elements); swizzled k-slices
    const int axo = (wr * 128 + lm) * 64;
    const int bxo = (wc * 64  + lm) * 64;
    const int ks0 = ((quad * 8)      ^ ((lm & 7) * 8));
    const int ks1 = ((32 + quad * 8) ^ ((lm & 7) * 8));

    // prologue: tile0 fully + tile1 early-5 rounds, drain to tile0
    STA(0, 0, 0); STA(0, 64, 0); STA(0, 128, 0); STA(0, 192, 0);
    STB(0, 0, 0); STB(0, 64, 0); STB(0, 128, 0); STB(0, 192, 0);
    STA(1, 0, 1); STA(1, 128, 1); STB(1, 0, 1); STA(1, 64, 1); STB(1, 64, 1);
    asm volatile("s_waitcnt vmcnt(5)" ::: "memory");
    __builtin_amdgcn_s_barrier();
    asm volatile("" ::: "memory");

    bf16x8 Af[4][2], Bf[4][2];
    for (int t = 0; t < NT; ++t) {
        const int b = t & 1;
        const __bf16* la = LA[b];
        const __bf16* lb = LB[b];
        // ---- P1: read A m0-3 (both k), B n0-1; MFMA quadrant (mL, nL)
        #pragma unroll
        for (int mi = 0; mi < 4; ++mi) {
            Af[mi][0] = *(const bf16x8*)(la + axo + mi * 1024 + ks0);
            Af[mi][1] = *(const bf16x8*)(la + axo + mi * 1024 + ks1);
        }
        #pragma unroll
        for (int ni = 0; ni < 2; ++ni) {
            Bf[ni][0] = *(const bf16x8*)(lb + bxo + ni * 1024 + ks0);
            Bf[ni][1] = *(const bf16x8*)(lb + bxo + ni * 1024 + ks1);
        }
        if (t + 1 < NT) { STA(b ^ 1, 192, t + 1); STB(b ^ 1, 128, t + 1); }
        __builtin_amdgcn_s_barrier();
        asm volatile("s_waitcnt lgkmcnt(0)" ::: "memory");
        __builtin_amdgcn_s_setprio(1);
        #pragma unroll
        for (int mi = 0; mi < 4; ++mi)
            #pragma unroll
            for (int ni = 0; ni < 2; ++ni) {
                acc[mi][ni] = mfma16(Af[mi][0], Bf[ni][0], acc[mi][ni]);
                acc[mi][ni] = mfma16(Af[mi][1], Bf[ni][1], acc[mi][ni]);
            }
        __builtin_amdgcn_s_setprio(0);
        __builtin_amdgcn_s_barrier();
        // ---- P2: read B n2-3; MFMA (mL, nH)
        #pragma unroll
        for (int ni = 2; ni < 4; ++ni) {
            Bf[ni][0] = *(const bf16x8*)(lb + bxo + ni * 1024 + ks0);
            Bf[ni][1] = *(const bf16x8*)(lb + bxo + ni * 1024 + ks1);
        }
        if (t + 1 < NT) STB(b ^ 1, 192, t + 1);
        if (t + 2 < NT) STA(b, 0, t + 2);
        __builtin_amdgcn_s_barrier();
        asm volatile("s_waitcnt lgkmcnt(0)" ::: "memory");
        __builtin_amdgcn_s_setprio(1);
        #pragma unroll
        for (int mi = 0; mi < 4; ++mi)
            #pragma unroll
            for (int ni = 2; ni < 4; ++ni) {
                acc[mi][ni] = mfma16(Af[mi][0], Bf[ni][0], acc[mi][ni]);
                acc[mi][ni] = mfma16(Af[mi][1], Bf[ni][1], acc[mi][ni]);
            }
        __builtin_amdgcn_s_setprio(0);
        __builtin_amdgcn_s_barrier();
        // ---- P3: read A m4-7; MFMA (mH, nL)
        #pragma unroll
        for (int mi = 0; mi < 4; ++mi) {
            Af[mi][0] = *(const bf16x8*)(la + axo + (mi + 4) * 1024 + ks0);
            Af[mi][1] = *(const bf16x8*)(la + axo + (mi + 4) * 1024 + ks1);
        }
        if (t + 2 < NT) { STA(b, 128, t + 2); STB(b, 0, t + 2); }
        __builtin_amdgcn_s_barrier();
        asm volatile("s_waitcnt lgkmcnt(0)" ::: "memory");
        __builtin_amdgcn_s_setprio(1);
        #pragma unroll
        for (int mi = 0; mi < 4; ++mi)
            #pragma unroll
            for (int ni = 0; ni < 2; ++ni) {
                acc[mi + 4][ni] = mfma16(Af[mi][0], Bf[ni][0], acc[mi + 4][ni]);
                acc[mi + 4][ni] = mfma16(Af[mi][1], Bf[ni][1], acc[mi + 4][ni]);
            }
        __builtin_amdgcn_s_setprio(0);
        __builtin_amdgcn_s_barrier();
        // ---- P4: MFMA (mH, nH); counted vmcnt; tile boundary
        if (t + 2 < NT) { STA(b, 64, t + 2); STB(b, 64, t + 2); }
        __builtin_amdgcn_s_barrier();
        __builtin_amdgcn_s_setprio(1);
        #pragma unroll
        for (int mi = 0; mi < 4; ++mi)
            #pragma unroll
            for (int ni = 2; ni < 4; ++ni) {
                acc[mi + 4][ni] = mfma16(Af[mi][0], Bf[ni][0], acc[mi + 4][ni]);
                acc[mi + 4][ni] = mfma16(Af[mi][1], Bf[ni][1], acc[mi + 4][ni]);
            }
        __builtin_amdgcn_s_setprio(0);
        if (t < NT - 2)       asm volatile("s_waitcnt vmcnt(5)" ::: "memory");
        else if (t == NT - 2) asm volatile("s_waitcnt vmcnt(0)" ::: "memory");
        __builtin_amdgcn_s_barrier();
        asm volatile("" ::: "memory");
    }

    float sc = 1.0f;
    if (ROPE) {
        const int colbase = n0 + wc * 64;       // 64-aligned, wave-uniform
        const int region  = (colbase < 2048) ? 0 : (colbase < 2560 ? 1 : 2);
        if (region < 2) {
            if (region == 0) sc = SCALE_Q;
            float invr[2];
            invr[0] = exp2f(-(float)lm        * L2IF) * INV2PI;
            invr[1] = exp2f(-(float)(16 + lm) * L2IF) * INV2PI;
            #pragma unroll
            for (int i = 0; i < 8; ++i)
                #pragma unroll
                for (int r = 0; r < 4; ++r) {
                    float tt = (float)((m0 + wr * 128 + i * 16 + quad * 4 + r) & 2047);
                    #pragma unroll
                    for (int jp = 0; jp < 2; ++jp) {
                        float aR = tt * invr[jp];
                        aR -= floorf(aR);                     // revolutions
                        float cs = __builtin_amdgcn_cosf(aR);
                        float sn = __builtin_amdgcn_sinf(aR);
                        float x1 = acc[i][jp][r], x2 = acc[i][jp + 2][r];
                        acc[i][jp][r]     = x1 * cs - x2 * sn;
                        acc[i][jp + 2][r] = x2 * cs + x1 * sn;
                    }
                }
        }
    }

    #pragma unroll
    for (int i = 0; i < 8; ++i)
        #pragma unroll
        for (int j = 0; j < 4; ++j)
            #pragma unroll
            for (int r = 0; r < 4; ++r) {
                int row = m0 + wr * 128 + i * 16 + quad * 4 + r;
                int col = n0 + wc * 64 + j * 16 + lm;
                if (OUT_F32)
                    ((float*)Cv)[(size_t)row * N + col] = acc[i][j][r];
                else
                    ((__bf16*)Cv)[(size_t)row * N + col] = (__bf16)(acc[i][j][r] * sc);
            }
}

// ---------------- GEMM: m97 128x128 structure (kept for O projection) -------
#define BK 32

template<bool ROPE, bool OUT_F32>
__global__ __launch_bounds__(256) void gemm_bt(
    const __bf16* __restrict__ A, const __bf16* __restrict__ Bw,
    void* __restrict__ Cv, int M, int N, int K)
{
    __shared__ __bf16 As[128 * BK];
    __shared__ __bf16 Bs[128 * BK];
    const int tid  = threadIdx.x;
    const int lane = tid & 63;
    const int w    = tid >> 6;
    const int lm   = lane & 15;
    const int quad = lane >> 4;
    const int wm   = (w >> 1) * 64;
    const int wn   = (w & 1) * 64;

    int bx, by;
    {
        int id  = blockIdx.x + gridDim.x * blockIdx.y;
        int xcd = id & 7;
        int j   = id >> 3;
        by = xcd * 4 + (j & 3);      // gy == 32
        bx = j >> 2;
    }
    const int m0 = by * 128;
    const int n0 = bx * 128;

    f32x4 acc[4][4];
    #pragma unroll
    for (int i = 0; i < 4; ++i)
        #pragma unroll
        for (int j = 0; j < 4; ++j)
            acc[i][j] = (f32x4){0.f, 0.f, 0.f, 0.f};

    const int srow = tid >> 2;
    const int sc8  = (tid & 3) * 8;
    const __bf16* gA0 = A  + (size_t)(m0 + srow) * K + sc8;
    const __bf16* gA1 = gA0 + (size_t)64 * K;
    const __bf16* gB0 = Bw + (size_t)(n0 + srow) * K + sc8;
    const __bf16* gB1 = gB0 + (size_t)64 * K;
    __bf16* lA0 = &As[srow * BK + sc8];
    __bf16* lA1 = &As[(srow + 64) * BK + sc8];
    __bf16* lB0 = &Bs[srow * BK + sc8];
    __bf16* lB1 = &Bs[(srow + 64) * BK + sc8];

    for (int k0 = 0; k0 < K; k0 += BK) {
        gld16(gA0 + k0, lA0);
        gld16(gA1 + k0, lA1);
        gld16(gB0 + k0, lB0);
        gld16(gB1 + k0, lB1);
        __syncthreads();

        bf16x8 af[4], bfr[4];
        #pragma unroll
        for (int i = 0; i < 4; ++i)
            af[i] = *(const bf16x8*)&As[(wm + i * 16 + lm) * BK + quad * 8];
        #pragma unroll
        for (int j = 0; j < 4; ++j)
            bfr[j] = *(const bf16x8*)&Bs[(wn + j * 16 + lm) * BK + quad * 8];
        #pragma unroll
        for (int i = 0; i < 4; ++i)
            #pragma unroll
            for (int j = 0; j < 4; ++j)
                acc[i][j] = mfma16(af[i], bfr[j], acc[i][j]);
        __syncthreads();
    }

    float sc = 1.0f;
    if (ROPE) {
        const int colbase = n0 + wn;
        const int region  = (colbase < 2048) ? 0 : (colbase < 2560 ? 1 : 2);
        if (region < 2) {
            if (region == 0) sc = SCALE_Q;
            float invr[2];
            invr[0] = exp2f(-(float)lm        * L2IF) * INV2PI;
            invr[1] = exp2f(-(float)(16 + lm) * L2IF) * INV2PI;
            #pragma unroll
            for (int i = 0; i < 4; ++i)
                #pragma unroll
                for (int r = 0; r < 4; ++r) {
                    float t = (float)((m0 + wm + i * 16 + quad * 4 + r) & 2047);
                    #pragma unroll
                    for (int jp = 0; jp < 2; ++jp) {
                        float a = t * invr[jp];
                        a -= floorf(a);
                        float cs = __builtin_amdgcn_cosf(a);
                        float sn = __builtin_amdgcn_sinf(a);
                        float x1 = acc[i][jp][r], x2 = acc[i][jp + 2][r];
                        acc[i][jp][r]     = x1 * cs - x2 * sn;
                        acc[i][jp + 2][r] = x2 * cs + x1 * sn;
                    }
                }
        }
    }

    #pragma unroll
    for (int i = 0; i < 4; ++i)
        #pragma unroll
        for (int j = 0; j < 4; ++j)
            #pragma unroll
            for (int r = 0; r < 4; ++r) {
                int row = m0 + wm + i * 16 + quad * 4 + r;
                int col = n0 + wn + j * 16 + lm;
                if (OUT_F32)
                    ((float*)Cv)[(size_t)row * N + col] = acc[i][j][r];
                else
                    ((__bf16*)Cv)[(size_t)row * N + col] = (__bf16)(acc[i][j][r] * sc);
            }
}

// ---------------- V transpose: [4096 tok][512 d] (stride 3072) -> [512][4096]
__global__ __launch_bounds__(256) void transpose_kernel(
    const __bf16* __restrict__ in, __bf16* __restrict__ out, int rowstride)
{
    __shared__ __bf16 T[64][72];
    const int t0 = blockIdx.x * 64;
    const int d0 = blockIdx.y * 64;
    const int r = threadIdx.x >> 2, c = (threadIdx.x & 3) * 16;
    *(int4*)&T[r][c]     = *(const int4*)(in + (size_t)(t0 + r) * rowstride + d0 + c);
    *(int4*)&T[r][c + 8] = *(const int4*)(in + (size_t)(t0 + r) * rowstride + d0 + c + 8);
    __syncthreads();
    bf16x8 o0, o1;
    #pragma unroll
    for (int i = 0; i < 8; ++i) { o0[i] = T[c + i][r]; o1[i] = T[c + 8 + i][r]; }
    *(bf16x8*)(out + (size_t)(d0 + r) * 4096 + t0 + c)     = o0;
    *(bf16x8*)(out + (size_t)(d0 + r) * 4096 + t0 + c + 8) = o1;
}

// ---------------- Flash attention (ROUND-8: fused paired tiles) -------------
// Transposed scores: St = mfma(A=K, B=Q) -> lane holds (kv=quad*4+r, q=lm).
// Paired q-blocks share one K/V fragment read set per tile (the LDS hot path).
#define RS  72
#define PKS 72

__device__ inline void attn_tile(
    const bf16x8 (&qf)[2], f32x4 (&oacc)[4], float& l,
    int qbase, int k0, int w, int lm, int quad,
    const __bf16* Ks, const __bf16* Vs, __bf16* Ptw)
{
    f32x4 st[4];
    #pragma unroll
    for (int n = 0; n < 4; ++n)
        st[n] = (f32x4){0.f, 0.f, 0.f, 0.f};

    #pragma unroll
    for (int n = 0; n < 4; ++n) {
        bf16x8 kf0 = *(const bf16x8*)&Ks[(n * 16 + lm) * RS + quad * 8];
        bf16x8 kf1 = *(const bf16x8*)&Ks[(n * 16 + lm) * RS + 32 + quad * 8];
        st[n] = mfma16(kf0, qf[0], st[n]);
        st[n] = mfma16(kf1, qf[1], st[n]);
    }

    const int qi = qbase + w * 16 + lm;
    const bool any_mask = (k0 + 63 > qbase + w * 16);
    #pragma unroll
    for (int n = 0; n < 4; ++n) {
        const int kv0 = k0 + n * 16 + quad * 4;
        float e0, e1, e2, e3;
        if (any_mask) {
            e0 = (kv0     > qi) ? 0.f : __builtin_amdgcn_exp2f(st[n][0]);
            e1 = (kv0 + 1 > qi) ? 0.f : __builtin_amdgcn_exp2f(st[n][1]);
            e2 = (kv0 + 2 > qi) ? 0.f : __builtin_amdgcn_exp2f(st[n][2]);
            e3 = (kv0 + 3 > qi) ? 0.f : __builtin_amdgcn_exp2f(st[n][3]);
        } else {
            e0 = __builtin_amdgcn_exp2f(st[n][0]); e1 = __builtin_amdgcn_exp2f(st[n][1]);
            e2 = __builtin_amdgcn_exp2f(st[n][2]); e3 = __builtin_amdgcn_exp2f(st[n][3]);
        }
        l += (e0 + e1) + (e2 + e3);
        *(bf16x4*)&Ptw[lm * PKS + n * 16 + quad * 4] = pk4(e0, e1, e2, e3);
    }

    bf16x8 pf0 = *(const bf16x8*)&Ptw[lm * PKS + quad * 8];
    bf16x8 pf1 = *(const bf16x8*)&Ptw[lm * PKS + 32 + quad * 8];
    #pragma unroll
    for (int dt = 0; dt < 4; ++dt) {
        bf16x8 vf0 = *(const bf16x8*)&Vs[(dt * 16 + lm) * RS + quad * 8];
        bf16x8 vf1 = *(const bf16x8*)&Vs[(dt * 16 + lm) * RS + 32 + quad * 8];
        oacc[dt] = mfma16(vf0, pf0, oacc[dt]);
        oacc[dt] = mfma16(vf1, pf1, oacc[dt]);
    }
}

// Fused pair: one K/V fragment read set feeds both q-blocks.
// B (high q-block) is never masked here (k0 < ntA*64 <= qbB always).
__device__ inline void attn_tile2(
    const bf16x8 (&qfA)[2], const bf16x8 (&qfB)[2],
    f32x4 (&oA)[4], f32x4 (&oB)[4], float& lA, float& lB,
    int qbA, int k0, int w, int lm, int quad,
    const __bf16* Ks, const __bf16* Vs, __bf16* PtA, __bf16* PtB)
{
    f32x4 stA[4], stB[4];
    #pragma unroll
    for (int n = 0; n < 4; ++n) {
        stA[n] = (f32x4){0.f, 0.f, 0.f, 0.f};
        stB[n] = (f32x4){0.f, 0.f, 0.f, 0.f};
    }

    #pragma unroll
    for (int n = 0; n < 4; ++n) {
        bf16x8 kf0 = *(const bf16x8*)&Ks[(n * 16 + lm) * RS + quad * 8];
        bf16x8 kf1 = *(const bf16x8*)&Ks[(n * 16 + lm) * RS + 32 + quad * 8];
        stB[n] = mfma16(kf0, qfB[0], stB[n]);
        stB[n] = mfma16(kf1, qfB[1], stB[n]);
        stA[n] = mfma16(kf0, qfA[0], stA[n]);
        stA[n] = mfma16(kf1, qfA[1], stA[n]);
    }

    #pragma unroll
    for (int n = 0; n < 4; ++n) {
        float e0 = __builtin_amdgcn_exp2f(stB[n][0]);
        float e1 = __builtin_amdgcn_exp2f(stB[n][1]);
        float e2 = __builtin_amdgcn_exp2f(stB[n][2]);
        float e3 = __builtin_amdgcn_exp2f(stB[n][3]);
        lB += (e0 + e1) + (e2 + e3);
        *(bf16x4*)&PtB[lm * PKS + n * 16 + quad * 4] = pk4(e0, e1, e2, e3);
    }

    const int qiA = qbA + w * 16 + lm;
    const bool maskA = (k0 + 63 > qbA + w * 16);
    #pragma unroll
    for (int n = 0; n < 4; ++n) {
        const int kv0 = k0 + n * 16 + quad * 4;
        float e0, e1, e2, e3;
        if (maskA) {
            e0 = (kv0     > qiA) ? 0.f : __builtin_amdgcn_exp2f(stA[n][0]);
            e1 = (kv0 + 1 > qiA) ? 0.f : __builtin_amdgcn_exp2f(stA[n][1]);
            e2 = (kv0 + 2 > qiA) ? 0.f : __builtin_amdgcn_exp2f(stA[n][2]);
            e3 = (kv0 + 3 > qiA) ? 0.f : __builtin_amdgcn_exp2f(stA[n][3]);
        } else {
            e0 = __builtin_amdgcn_exp2f(stA[n][0]); e1 = __builtin_amdgcn_exp2f(stA[n][1]);
            e2 = __builtin_amdgcn_exp2f(stA[n][2]); e3 = __builtin_amdgcn_exp2f(stA[n][3]);
        }
        lA += (e0 + e1) + (e2 + e3);
        *(bf16x4*)&PtA[lm * PKS + n * 16 + quad * 4] = pk4(e0, e1, e2, e3);
    }

    bf16x8 pB0 = *(const bf16x8*)&PtB[lm * PKS + quad * 8];
    bf16x8 pB1 = *(const bf16x8*)&PtB[lm * PKS + 32 + quad * 8];
    bf16x8 pA0 = *(const bf16x8*)&PtA[lm * PKS + quad * 8];
    bf16x8 pA1 = *(const bf16x8*)&PtA[lm * PKS + 32 + quad * 8];
    #pragma unroll
    for (int dt = 0; dt < 4; ++dt) {
        bf16x8 vf0 = *(const bf16x8*)&Vs[(dt * 16 + lm) * RS + quad * 8];
        bf16x8 vf1 = *(const bf16x8*)&Vs[(dt * 16 + lm) * RS + 32 + quad * 8];
        oB[dt] = mfma16(vf0, pB0, oB[dt]);
        oB[dt] = mfma16(vf1, pB1, oB[dt]);
        oA[dt] = mfma16(vf0, pA0, oA[dt]);
        oA[dt] = mfma16(vf1, pA1, oA[dt]);
    }
}

__device__ inline void attn_epilogue(
    f32x4 (&oacc)[4], float l,
    int qbase, int w, int lm, int quad, int b, int h, __bf16* o)
{
    float ls = l;
    ls += __shfl_xor(ls, 16);
    ls += __shfl_xor(ls, 32);
    float rinv = 1.0f / ls;
    const size_t rowbase = (size_t)(b * 2048 + qbase + w * 16 + lm) * 2048 + h * 64;
    #pragma unroll
    for (int dt = 0; dt < 4; ++dt) {
        *(bf16x4*)(o + rowbase + dt * 16 + quad * 4) =
            pk4(oacc[dt][0] * rinv, oacc[dt][1] * rinv,
                oacc[dt][2] * rinv, oacc[dt][3] * rinv);
    }
}

__global__ __launch_bounds__(512, 4) void attn_kernel(
    const __bf16* __restrict__ qkv, const __bf16* __restrict__ vt,
    __bf16* __restrict__ o)
{
    __shared__ __bf16 Ks[2][64 * RS];
    __shared__ __bf16 Vs[2][64 * RS];
    __shared__ __bf16 Pt[8][2][16 * PKS];
    const int tid  = threadIdx.x;
    const int w    = tid >> 6;
    const int lane = tid & 63;
    const int lm   = lane & 15;
    const int quad = lane >> 4;
    const int p = blockIdx.x, h = blockIdx.y, b = blockIdx.z;
    const int kvh = h >> 2;
    const int qbA = p * 128, qbB = (15 - p) * 128;
    const int ntA = 2 * p + 2, ntB = 32 - 2 * p;
    __bf16* PtwB = &Pt[w][0][0];
    __bf16* PtwA = &Pt[w][1][0];

    bf16x8 qfA[2], qfB[2];
    #pragma unroll
    for (int kh = 0; kh < 2; ++kh) {
        qfA[kh] = *(const bf16x8*)(qkv + (size_t)(b * 2048 + qbA + w * 16 + lm) * 3072
                                      + h * 64 + kh * 32 + quad * 8);
        qfB[kh] = *(const bf16x8*)(qkv + (size_t)(b * 2048 + qbB + w * 16 + lm) * 3072
                                      + h * 64 + kh * 32 + quad * 8);
    }

    f32x4 oA[4], oB[4];
    float lA = 0.f, lB = 0.f;
    #pragma unroll
    for (int j = 0; j < 4; ++j) {
        oA[j] = (f32x4){0.f, 0.f, 0.f, 0.f};
        oB[j] = (f32x4){0.f, 0.f, 0.f, 0.f};
    }

    const int srow = tid >> 3;
    const int scol = (tid & 7) * 8;
    const __bf16* kbase = qkv + (size_t)(b * 2048) * 3072 + 2048 + kvh * 64;
    const __bf16* vbase = vt  + (size_t)(kvh * 64 + srow) * 4096 + b * 2048;

    int4 kr0, vr0;
    kr0 = *(const int4*)(kbase + (size_t)srow * 3072 + scol);
    vr0 = *(const int4*)(vbase + scol);

    for (int kt = 0; kt < ntB; ++kt) {
        const int c = kt & 1;
        const int k0 = kt * 64;
        *(int4*)&Ks[c][srow * RS + scol] = kr0;
        *(int4*)&Vs[c][srow * RS + scol] = vr0;
        if (kt + 1 < ntB) {
            kr0 = *(const int4*)(kbase + (size_t)(k0 + 64 + srow) * 3072 + scol);
            vr0 = *(const int4*)(vbase + k0 + 64 + scol);
        }
        __syncthreads();
        if (kt < ntA)
            attn_tile2(qfA, qfB, oA, oB, lA, lB, qbA, k0, w, lm, quad,
                       Ks[c], Vs[c], PtwA, PtwB);
        else
            attn_tile(qfB, oB, lB, qbB, k0, w, lm, quad, Ks[c], Vs[c], PtwB);
    }

    attn_epilogue(oA, lA, qbA, w, lm, quad, b, h, o);
    attn_epilogue(oB, lB, qbB, w, lm, quad, b, h, o);
}

// ---------------------------------------------------------------------------
extern "C" void kernel_launch(void* const* d_in, const int* in_sizes, int n_in,
                              void* d_out, int out_size, void* d_ws, size_t ws_size,
                              hipStream_t stream)
{
    const float* x  = (const float*)d_in[0];
    const float* Wq = (const float*)d_in[1];
    const float* Wk = (const float*)d_in[2];
    const float* Wv = (const float*)d_in[3];
    const float* Wo = (const float*)d_in[4];

    const size_t Mi = 1u << 20;
    // d_out (32 MiB fp32) is scratch until the final GEMM writes it.
    char* ob = (char*)d_out;
    __bf16* xb    = (__bf16*)ob;              // 16 MiB  [4096][2048]
    __bf16* wqkvb = (__bf16*)(ob + 16 * Mi);  // 12 MiB  [3072][2048]
    __bf16* vt    = (__bf16*)(ob + 28 * Mi);  //  4 MiB  [512][4096]
    // d_ws (>= 40 MiB, proven)
    char* ws = (char*)d_ws;
    __bf16* qkvc = (__bf16*)ws;               // 24 MiB  [4096][3072]  Q|K|V
    __bf16* aws  = (__bf16*)(ws + 24 * Mi);   // 16 MiB  [4096][2048]
    __bf16* wob  = (__bf16*)ws;               //  8 MiB, reuses qkvc after attn

    dim3 blk(256);
    cvt4_kernel<<<14336, blk, 0, stream>>>(x, Wq, Wk, Wv, xb, wqkvb);
    gemm256<true, false><<<dim3(12, 16), dim3(512), 0, stream>>>(xb, wqkvb, qkvc, 4096, 3072, 2048);
    transpose_kernel<<<dim3(64, 8), blk, 0, stream>>>(qkvc + 2560, vt, 3072);
    attn_kernel<<<dim3(8, 32, 2), dim3(512), 0, stream>>>(qkvc, vt, aws);
    cvt_kernel<<<4096, blk, 0, stream>>>(Wo, wob, 1048576);
    gemm_bt<false, true><<<dim3(16, 32), blk, 0, stream>>>(aws, wob, d_out, 4096, 2048, 2048);
}

// Round 5
// 292.705 us; speedup vs baseline: 1.1838x; 1.0616x over previous
//
#include <hip/hip_runtime.h>

// ---------------------------------------------------------------------------
// GQA forward, fp32 I/O, bf16 MFMA compute.
// B=2 S=2048 D=2048 HQ=32 HKV=8 HD=64.
// cvt4 -> QKV GEMM (256x256 4-phase pipelined, counted vmcnt, XOR LDS swizzle,
// setprio, fused RoPE) -> V transpose -> flash attn (ROUND-9: XOR-swizzled
// K/V/P LDS, RS=64, fused paired-tile) -> cvt(Wo) -> O GEMM (ROUND-9: 256x128
// 4-phase pipelined, 256 blocks = 1/CU, counted vmcnt L=6).
// ---------------------------------------------------------------------------

typedef __bf16 bf16x8 __attribute__((ext_vector_type(8)));
typedef __bf16 bf16x4 __attribute__((ext_vector_type(4)));
typedef float f32x4 __attribute__((ext_vector_type(4)));

__device__ inline f32x4 mfma16(bf16x8 a, bf16x8 b, f32x4 c) {
    return __builtin_amdgcn_mfma_f32_16x16x32_bf16(a, b, c, 0, 0, 0);
}

__device__ inline void gld16(const __bf16* g, __bf16* l) {
    __builtin_amdgcn_global_load_lds(
        (const __attribute__((address_space(1))) void*)g,
        (__attribute__((address_space(3))) void*)l, 16, 0, 0);
}

__device__ inline bf16x4 pk4(float a, float b, float c, float d) {
    bf16x4 r; r[0] = (__bf16)a; r[1] = (__bf16)b; r[2] = (__bf16)c; r[3] = (__bf16)d;
    return r;
}

// 1/sqrt(64) * log2(e): attn computes exp2(score) = exp(qk/8)
#define SCALE_Q 0.18033688011112042f
#define L2IF    0.4152410118609203f    // log2(10000)/32
#define INV2PI  0.15915494309189535f

// ---------------- fused fp32->bf16 for x, Wq, Wk, Wv ------------------------
__global__ void cvt4_kernel(const float* __restrict__ x,  const float* __restrict__ wq,
                            const float* __restrict__ wk, const float* __restrict__ wv,
                            __bf16* __restrict__ xb, __bf16* __restrict__ wqkvb)
{
    int i = blockIdx.x * blockDim.x + threadIdx.x;
    const float* src; __bf16* dst;
    if (i < 2097152)      { src = x  + (size_t)i * 4;  dst = xb + (size_t)i * 4; }
    else if (i < 3145728) { int j = i - 2097152; src = wq + (size_t)j * 4; dst = wqkvb + (size_t)j * 4; }
    else if (i < 3407872) { int j = i - 3145728; src = wk + (size_t)j * 4; dst = wqkvb + 4194304 + (size_t)j * 4; }
    else                  { int j = i - 3407872; src = wv + (size_t)j * 4; dst = wqkvb + 5242880 + (size_t)j * 4; }
    float4 f = *(const float4*)src;
    *(bf16x4*)dst = pk4(f.x, f.y, f.z, f.w);
}

__global__ void cvt_kernel(const float* __restrict__ in, __bf16* __restrict__ out, int n4)
{
    int i = blockIdx.x * blockDim.x + threadIdx.x;
    if (i >= n4) return;
    float4 f = ((const float4*)in)[i];
    ((bf16x4*)out)[i] = pk4(f.x, f.y, f.z, f.w);
}

// ---------------- 256x256 4-phase GEMM (QKV): C = A[M,K] * Bw[N,K]^T --------
template<bool ROPE, bool OUT_F32>
__global__ __launch_bounds__(512, 2) void gemm256(
    const __bf16* __restrict__ A, const __bf16* __restrict__ Bw,
    void* __restrict__ Cv, int M, int N, int K)
{
    __shared__ __bf16 LA[2][16384];
    __shared__ __bf16 LB[2][16384];
    const int tid  = threadIdx.x;
    const int lane = tid & 63;
    const int w    = tid >> 6;
    const int lm   = lane & 15;
    const int quad = lane >> 4;
    const int wr   = w >> 2;     // 0..1
    const int wc   = w & 3;      // 0..3

    int bx, by;
    {
        int nwg = gridDim.x * gridDim.y;        // must be %8 == 0
        int id  = blockIdx.x + gridDim.x * blockIdx.y;
        int q   = nwg >> 3;
        int swz = (id & 7) * q + (id >> 3);
        by = swz / gridDim.x;
        bx = swz - by * gridDim.x;
    }
    const int m0 = by * 256;
    const int n0 = bx * 256;
    const int NT = K >> 6;

    const int srow = tid >> 3;
    const int scol = ((tid & 7) ^ (srow & 7)) * 8;   // pre-swizzled source col
    const int ldst = tid * 8;                        // linear LDS dest (elems)
    const __bf16* ga = A  + (size_t)(m0 + srow) * K + scol;
    const __bf16* gb = Bw + (size_t)(n0 + srow) * K + scol;

    auto STA = [&](int bf, int r, int u) {
        gld16(ga + (size_t)r * K + u * 64, &LA[bf][r * 64 + ldst]);
    };
    auto STB = [&](int bf, int r, int u) {
        gld16(gb + (size_t)r * K + u * 64, &LB[bf][r * 64 + ldst]);
    };

    f32x4 acc[8][4];
    #pragma unroll
    for (int i = 0; i < 8; ++i)
        #pragma unroll
        for (int j = 0; j < 4; ++j)
            acc[i][j] = (f32x4){0.f, 0.f, 0.f, 0.f};

    const int axo = (wr * 128 + lm) * 64;
    const int bxo = (wc * 64  + lm) * 64;
    const int ks0 = ((quad * 8)      ^ ((lm & 7) * 8));
    const int ks1 = ((32 + quad * 8) ^ ((lm & 7) * 8));

    STA(0, 0, 0); STA(0, 64, 0); STA(0, 128, 0); STA(0, 192, 0);
    STB(0, 0, 0); STB(0, 64, 0); STB(0, 128, 0); STB(0, 192, 0);
    STA(1, 0, 1); STA(1, 128, 1); STB(1, 0, 1); STA(1, 64, 1); STB(1, 64, 1);
    asm volatile("s_waitcnt vmcnt(5)" ::: "memory");
    __builtin_amdgcn_s_barrier();
    asm volatile("" ::: "memory");

    bf16x8 Af[4][2], Bf[4][2];
    for (int t = 0; t < NT; ++t) {
        const int b = t & 1;
        const __bf16* la = LA[b];
        const __bf16* lb = LB[b];
        #pragma unroll
        for (int mi = 0; mi < 4; ++mi) {
            Af[mi][0] = *(const bf16x8*)(la + axo + mi * 1024 + ks0);
            Af[mi][1] = *(const bf16x8*)(la + axo + mi * 1024 + ks1);
        }
        #pragma unroll
        for (int ni = 0; ni < 2; ++ni) {
            Bf[ni][0] = *(const bf16x8*)(lb + bxo + ni * 1024 + ks0);
            Bf[ni][1] = *(const bf16x8*)(lb + bxo + ni * 1024 + ks1);
        }
        if (t + 1 < NT) { STA(b ^ 1, 192, t + 1); STB(b ^ 1, 128, t + 1); }
        __builtin_amdgcn_s_barrier();
        asm volatile("s_waitcnt lgkmcnt(0)" ::: "memory");
        __builtin_amdgcn_s_setprio(1);
        #pragma unroll
        for (int mi = 0; mi < 4; ++mi)
            #pragma unroll
            for (int ni = 0; ni < 2; ++ni) {
                acc[mi][ni] = mfma16(Af[mi][0], Bf[ni][0], acc[mi][ni]);
                acc[mi][ni] = mfma16(Af[mi][1], Bf[ni][1], acc[mi][ni]);
            }
        __builtin_amdgcn_s_setprio(0);
        __builtin_amdgcn_s_barrier();
        #pragma unroll
        for (int ni = 2; ni < 4; ++ni) {
            Bf[ni][0] = *(const bf16x8*)(lb + bxo + ni * 1024 + ks0);
            Bf[ni][1] = *(const bf16x8*)(lb + bxo + ni * 1024 + ks1);
        }
        if (t + 1 < NT) STB(b ^ 1, 192, t + 1);
        if (t + 2 < NT) STA(b, 0, t + 2);
        __builtin_amdgcn_s_barrier();
        asm volatile("s_waitcnt lgkmcnt(0)" ::: "memory");
        __builtin_amdgcn_s_setprio(1);
        #pragma unroll
        for (int mi = 0; mi < 4; ++mi)
            #pragma unroll
            for (int ni = 2; ni < 4; ++ni) {
                acc[mi][ni] = mfma16(Af[mi][0], Bf[ni][0], acc[mi][ni]);
                acc[mi][ni] = mfma16(Af[mi][1], Bf[ni][1], acc[mi][ni]);
            }
        __builtin_amdgcn_s_setprio(0);
        __builtin_amdgcn_s_barrier();
        #pragma unroll
        for (int mi = 0; mi < 4; ++mi) {
            Af[mi][0] = *(const bf16x8*)(la + axo + (mi + 4) * 1024 + ks0);
            Af[mi][1] = *(const bf16x8*)(la + axo + (mi + 4) * 1024 + ks1);
        }
        if (t + 2 < NT) { STA(b, 128, t + 2); STB(b, 0, t + 2); }
        __builtin_amdgcn_s_barrier();
        asm volatile("s_waitcnt lgkmcnt(0)" ::: "memory");
        __builtin_amdgcn_s_setprio(1);
        #pragma unroll
        for (int mi = 0; mi < 4; ++mi)
            #pragma unroll
            for (int ni = 0; ni < 2; ++ni) {
                acc[mi + 4][ni] = mfma16(Af[mi][0], Bf[ni][0], acc[mi + 4][ni]);
                acc[mi + 4][ni] = mfma16(Af[mi][1], Bf[ni][1], acc[mi + 4][ni]);
            }
        __builtin_amdgcn_s_setprio(0);
        __builtin_amdgcn_s_barrier();
        if (t + 2 < NT) { STA(b, 64, t + 2); STB(b, 64, t + 2); }
        __builtin_amdgcn_s_barrier();
        __builtin_amdgcn_s_setprio(1);
        #pragma unroll
        for (int mi = 0; mi < 4; ++mi)
            #pragma unroll
            for (int ni = 2; ni < 4; ++ni) {
                acc[mi + 4][ni] = mfma16(Af[mi][0], Bf[ni][0], acc[mi + 4][ni]);
                acc[mi + 4][ni] = mfma16(Af[mi][1], Bf[ni][1], acc[mi + 4][ni]);
            }
        __builtin_amdgcn_s_setprio(0);
        if (t < NT - 2)       asm volatile("s_waitcnt vmcnt(5)" ::: "memory");
        else if (t == NT - 2) asm volatile("s_waitcnt vmcnt(0)" ::: "memory");
        __builtin_amdgcn_s_barrier();
        asm volatile("" ::: "memory");
    }

    float sc = 1.0f;
    if (ROPE) {
        const int colbase = n0 + wc * 64;       // 64-aligned, wave-uniform
        const int region  = (colbase < 2048) ? 0 : (colbase < 2560 ? 1 : 2);
        if (region < 2) {
            if (region == 0) sc = SCALE_Q;
            float invr[2];
            invr[0] = exp2f(-(float)lm        * L2IF) * INV2PI;
            invr[1] = exp2f(-(float)(16 + lm) * L2IF) * INV2PI;
            #pragma unroll
            for (int i = 0; i < 8; ++i)
                #pragma unroll
                for (int r = 0; r < 4; ++r) {
                    float tt = (float)((m0 + wr * 128 + i * 16 + quad * 4 + r) & 2047);
                    #pragma unroll
                    for (int jp = 0; jp < 2; ++jp) {
                        float aR = tt * invr[jp];
                        aR -= floorf(aR);                     // revolutions
                        float cs = __builtin_amdgcn_cosf(aR);
                        float sn = __builtin_amdgcn_sinf(aR);
                        float x1 = acc[i][jp][r], x2 = acc[i][jp + 2][r];
                        acc[i][jp][r]     = x1 * cs - x2 * sn;
                        acc[i][jp + 2][r] = x2 * cs + x1 * sn;
                    }
                }
        }
    }

    #pragma unroll
    for (int i = 0; i < 8; ++i)
        #pragma unroll
        for (int j = 0; j < 4; ++j)
            #pragma unroll
            for (int r = 0; r < 4; ++r) {
                int row = m0 + wr * 128 + i * 16 + quad * 4 + r;
                int col = n0 + wc * 64 + j * 16 + lm;
                if (OUT_F32)
                    ((float*)Cv)[(size_t)row * N + col] = acc[i][j][r];
                else
                    ((__bf16*)Cv)[(size_t)row * N + col] = (__bf16)(acc[i][j][r] * sc);
            }
}

// ---------------- 256x128 4-phase GEMM (O proj): C fp32 ---------------------
// 512 thr = 8 waves (4 Mr x 2 Nc), per-wave 64x64 = acc[4][4]. Grid 16x16=256
// blocks = 1/CU. K-tile 64; loads/tile L=6 (A:4 rounds, B:2); vmcnt(6)/tile.
__global__ __launch_bounds__(512, 2) void gemm_o(
    const __bf16* __restrict__ A, const __bf16* __restrict__ Bw,
    float* __restrict__ C, int M, int N, int K)
{
    __shared__ __bf16 LA[2][16384];   // 256x64
    __shared__ __bf16 LB[2][8192];    // 128x64
    const int tid  = threadIdx.x;
    const int lane = tid & 63;
    const int w    = tid >> 6;
    const int lm   = lane & 15;
    const int quad = lane >> 4;
    const int wr   = w >> 1;     // 0..3
    const int wc   = w & 1;      // 0..1

    int bx, by;
    {
        int id  = blockIdx.x + gridDim.x * blockIdx.y;   // 256 wgs
        int swz = (id & 7) * 32 + (id >> 3);
        by = swz >> 4;
        bx = swz & 15;
    }
    const int m0 = by * 256;
    const int n0 = bx * 128;
    const int NT = K >> 6;

    const int srow = tid >> 3;
    const int scol = ((tid & 7) ^ (srow & 7)) * 8;
    const int ldst = tid * 8;
    const __bf16* ga = A  + (size_t)(m0 + srow) * K + scol;
    const __bf16* gb = Bw + (size_t)(n0 + srow) * K + scol;

    auto STA = [&](int bf, int r, int u) {
        gld16(ga + (size_t)r * K + u * 64, &LA[bf][r * 64 + ldst]);
    };
    auto STB = [&](int bf, int r, int u) {
        gld16(gb + (size_t)r * K + u * 64, &LB[bf][r * 64 + ldst]);
    };

    f32x4 acc[4][4];
    #pragma unroll
    for (int i = 0; i < 4; ++i)
        #pragma unroll
        for (int j = 0; j < 4; ++j)
            acc[i][j] = (f32x4){0.f, 0.f, 0.f, 0.f};

    const int axo = (wr * 64 + lm) * 64;
    const int bxo = (wc * 64 + lm) * 64;
    const int ks0 = ((quad * 8)      ^ ((lm & 7) * 8));
    const int ks1 = ((32 + quad * 8) ^ ((lm & 7) * 8));

    // prologue: t0 (6) + t1 (6); drain to t0
    STA(0, 0, 0); STA(0, 64, 0); STA(0, 128, 0); STA(0, 192, 0);
    STB(0, 0, 0); STB(0, 64, 0);
    STA(1, 0, 1); STA(1, 64, 1); STA(1, 128, 1); STA(1, 192, 1);
    STB(1, 0, 1); STB(1, 64, 1);
    asm volatile("s_waitcnt vmcnt(6)" ::: "memory");
    __builtin_amdgcn_s_barrier();
    asm volatile("" ::: "memory");

    bf16x8 Af[4][2], Bf[4][2];
    for (int t = 0; t < NT; ++t) {
        const int b = t & 1;
        const __bf16* la = LA[b];
        const __bf16* lb = LB[b];
        // ---- P1: read Af m0-1, Bf n0-1; MFMA (m01, n01)
        #pragma unroll
        for (int mi = 0; mi < 2; ++mi) {
            Af[mi][0] = *(const bf16x8*)(la + axo + mi * 1024 + ks0);
            Af[mi][1] = *(const bf16x8*)(la + axo + mi * 1024 + ks1);
        }
        #pragma unroll
        for (int ni = 0; ni < 2; ++ni) {
            Bf[ni][0] = *(const bf16x8*)(lb + bxo + ni * 1024 + ks0);
            Bf[ni][1] = *(const bf16x8*)(lb + bxo + ni * 1024 + ks1);
        }
        __builtin_amdgcn_s_barrier();
        asm volatile("s_waitcnt lgkmcnt(0)" ::: "memory");
        __builtin_amdgcn_s_setprio(1);
        #pragma unroll
        for (int mi = 0; mi < 2; ++mi)
            #pragma unroll
            for (int ni = 0; ni < 2; ++ni) {
                acc[mi][ni] = mfma16(Af[mi][0], Bf[ni][0], acc[mi][ni]);
                acc[mi][ni] = mfma16(Af[mi][1], Bf[ni][1], acc[mi][ni]);
            }
        __builtin_amdgcn_s_setprio(0);
        __builtin_amdgcn_s_barrier();
        // ---- P2: read Bf n2-3; MFMA (m01, n23)
        #pragma unroll
        for (int ni = 2; ni < 4; ++ni) {
            Bf[ni][0] = *(const bf16x8*)(lb + bxo + ni * 1024 + ks0);
            Bf[ni][1] = *(const bf16x8*)(lb + bxo + ni * 1024 + ks1);
        }
        __builtin_amdgcn_s_barrier();
        asm volatile("s_waitcnt lgkmcnt(0)" ::: "memory");
        __builtin_amdgcn_s_setprio(1);
        #pragma unroll
        for (int mi = 0; mi < 2; ++mi)
            #pragma unroll
            for (int ni = 2; ni < 4; ++ni) {
                acc[mi][ni] = mfma16(Af[mi][0], Bf[ni][0], acc[mi][ni]);
                acc[mi][ni] = mfma16(Af[mi][1], Bf[ni][1], acc[mi][ni]);
            }
        __builtin_amdgcn_s_setprio(0);
        __builtin_amdgcn_s_barrier();
        // ---- P3: read Af m2-3; stage B(t+2); MFMA (m23, n01)
        #pragma unroll
        for (int mi = 2; mi < 4; ++mi) {
            Af[mi][0] = *(const bf16x8*)(la + axo + mi * 1024 + ks0);
            Af[mi][1] = *(const bf16x8*)(la + axo + mi * 1024 + ks1);
        }
        if (t + 2 < NT) { STB(b, 0, t + 2); STB(b, 64, t + 2); }
        __builtin_amdgcn_s_barrier();
        asm volatile("s_waitcnt lgkmcnt(0)" ::: "memory");
        __builtin_amdgcn_s_setprio(1);
        #pragma unroll
        for (int mi = 2; mi < 4; ++mi)
            #pragma unroll
            for (int ni = 0; ni < 2; ++ni) {
                acc[mi][ni] = mfma16(Af[mi][0], Bf[ni][0], acc[mi][ni]);
                acc[mi][ni] = mfma16(Af[mi][1], Bf[ni][1], acc[mi][ni]);
            }
        __builtin_amdgcn_s_setprio(0);
        __builtin_amdgcn_s_barrier();
        // ---- P4: stage A(t+2); MFMA (m23, n23); counted vmcnt
        if (t + 2 < NT) {
            STA(b, 0, t + 2); STA(b, 64, t + 2);
            STA(b, 128, t + 2); STA(b, 192, t + 2);
        }
        __builtin_amdgcn_s_setprio(1);
        #pragma unroll
        for (int mi = 2; mi < 4; ++mi)
            #pragma unroll
            for (int ni = 2; ni < 4; ++ni) {
                acc[mi][ni] = mfma16(Af[mi][0], Bf[ni][0], acc[mi][ni]);
                acc[mi][ni] = mfma16(Af[mi][1], Bf[ni][1], acc[mi][ni]);
            }
        __builtin_amdgcn_s_setprio(0);
        if (t < NT - 2) asm volatile("s_waitcnt vmcnt(6)" ::: "memory");
        else            asm volatile("s_waitcnt vmcnt(0)" ::: "memory");
        __builtin_amdgcn_s_barrier();
        asm volatile("" ::: "memory");
    }

    #pragma unroll
    for (int i = 0; i < 4; ++i)
        #pragma unroll
        for (int j = 0; j < 4; ++j)
            #pragma unroll
            for (int r = 0; r < 4; ++r) {
                int row = m0 + wr * 64 + i * 16 + quad * 4 + r;
                int col = n0 + wc * 64 + j * 16 + lm;
                C[(size_t)row * N + col] = acc[i][j][r];
            }
}

// ---------------- V transpose: [4096 tok][512 d] (stride 3072) -> [512][4096]
__global__ __launch_bounds__(256) void transpose_kernel(
    const __bf16* __restrict__ in, __bf16* __restrict__ out, int rowstride)
{
    __shared__ __bf16 T[64][72];
    const int t0 = blockIdx.x * 64;
    const int d0 = blockIdx.y * 64;
    const int r = threadIdx.x >> 2, c = (threadIdx.x & 3) * 16;
    *(int4*)&T[r][c]     = *(const int4*)(in + (size_t)(t0 + r) * rowstride + d0 + c);
    *(int4*)&T[r][c + 8] = *(const int4*)(in + (size_t)(t0 + r) * rowstride + d0 + c + 8);
    __syncthreads();
    bf16x8 o0, o1;
    #pragma unroll
    for (int i = 0; i < 8; ++i) { o0[i] = T[c + i][r]; o1[i] = T[c + 8 + i][r]; }
    *(bf16x8*)(out + (size_t)(d0 + r) * 4096 + t0 + c)     = o0;
    *(bf16x8*)(out + (size_t)(d0 + r) * 4096 + t0 + c + 8) = o1;
}

// ---------------- Flash attention (ROUND-9: XOR-swizzled LDS) ---------------
// K/V/P tiles stored [row][64] with 16B-block XOR (block ^= row&7) -- the
// pattern measured at 0 bank conflicts in gemm256. Reg-staged stores swizzle
// the LDS side; global side stays linear.
#define RS  64
#define PKS 64

__device__ inline void attn_tile(
    const bf16x8 (&qf)[2], f32x4 (&oacc)[4], float& l,
    int qbase, int k0, int w, int lm, int quad,
    const __bf16* Ks, const __bf16* Vs, __bf16* Ptw)
{
    const int kb0 = (quad ^ (lm & 7)) * 8;
    const int kb1 = ((quad + 4) ^ (lm & 7)) * 8;
    f32x4 st[4];
    #pragma unroll
    for (int n = 0; n < 4; ++n)
        st[n] = (f32x4){0.f, 0.f, 0.f, 0.f};

    #pragma unroll
    for (int n = 0; n < 4; ++n) {
        bf16x8 kf0 = *(const bf16x8*)&Ks[(n * 16 + lm) * RS + kb0];
        bf16x8 kf1 = *(const bf16x8*)&Ks[(n * 16 + lm) * RS + kb1];
        st[n] = mfma16(kf0, qf[0], st[n]);
        st[n] = mfma16(kf1, qf[1], st[n]);
    }

    const int qi = qbase + w * 16 + lm;
    const bool any_mask = (k0 + 63 > qbase + w * 16);
    #pragma unroll
    for (int n = 0; n < 4; ++n) {
        const int kv0 = k0 + n * 16 + quad * 4;
        float e0, e1, e2, e3;
        if (any_mask) {
            e0 = (kv0     > qi) ? 0.f : __builtin_amdgcn_exp2f(st[n][0]);
            e1 = (kv0 + 1 > qi) ? 0.f : __builtin_amdgcn_exp2f(st[n][1]);
            e2 = (kv0 + 2 > qi) ? 0.f : __builtin_amdgcn_exp2f(st[n][2]);
            e3 = (kv0 + 3 > qi) ? 0.f : __builtin_amdgcn_exp2f(st[n][3]);
        } else {
            e0 = __builtin_amdgcn_exp2f(st[n][0]); e1 = __builtin_amdgcn_exp2f(st[n][1]);
            e2 = __builtin_amdgcn_exp2f(st[n][2]); e3 = __builtin_amdgcn_exp2f(st[n][3]);
        }
        l += (e0 + e1) + (e2 + e3);
        *(bf16x4*)&Ptw[lm * PKS + ((n * 4 + quad) ^ ((lm & 7) << 1)) * 4] =
            pk4(e0, e1, e2, e3);
    }

    bf16x8 pf0 = *(const bf16x8*)&Ptw[lm * PKS + kb0];
    bf16x8 pf1 = *(const bf16x8*)&Ptw[lm * PKS + kb1];
    #pragma unroll
    for (int dt = 0; dt < 4; ++dt) {
        bf16x8 vf0 = *(const bf16x8*)&Vs[(dt * 16 + lm) * RS + kb0];
        bf16x8 vf1 = *(const bf16x8*)&Vs[(dt * 16 + lm) * RS + kb1];
        oacc[dt] = mfma16(vf0, pf0, oacc[dt]);
        oacc[dt] = mfma16(vf1, pf1, oacc[dt]);
    }
}

// Fused pair: one K/V fragment read set feeds both q-blocks.
__device__ inline void attn_tile2(
    const bf16x8 (&qfA)[2], const bf16x8 (&qfB)[2],
    f32x4 (&oA)[4], f32x4 (&oB)[4], float& lA, float& lB,
    int qbA, int k0, int w, int lm, int quad,
    const __bf16* Ks, const __bf16* Vs, __bf16* PtA, __bf16* PtB)
{
    const int kb0 = (quad ^ (lm & 7)) * 8;
    const int kb1 = ((quad + 4) ^ (lm & 7)) * 8;
    f32x4 stA[4], stB[4];
    #pragma unroll
    for (int n = 0; n < 4; ++n) {
        stA[n] = (f32x4){0.f, 0.f, 0.f, 0.f};
        stB[n] = (f32x4){0.f, 0.f, 0.f, 0.f};
    }

    #pragma unroll
    for (int n = 0; n < 4; ++n) {
        bf16x8 kf0 = *(const bf16x8*)&Ks[(n * 16 + lm) * RS + kb0];
        bf16x8 kf1 = *(const bf16x8*)&Ks[(n * 16 + lm) * RS + kb1];
        stB[n] = mfma16(kf0, qfB[0], stB[n]);
        stB[n] = mfma16(kf1, qfB[1], stB[n]);
        stA[n] = mfma16(kf0, qfA[0], stA[n]);
        stA[n] = mfma16(kf1, qfA[1], stA[n]);
    }

    #pragma unroll
    for (int n = 0; n < 4; ++n) {
        float e0 = __builtin_amdgcn_exp2f(stB[n][0]);
        float e1 = __builtin_amdgcn_exp2f(stB[n][1]);
        float e2 = __builtin_amdgcn_exp2f(stB[n][2]);
        float e3 = __builtin_amdgcn_exp2f(stB[n][3]);
        lB += (e0 + e1) + (e2 + e3);
        *(bf16x4*)&PtB[lm * PKS + ((n * 4 + quad) ^ ((lm & 7) << 1)) * 4] =
            pk4(e0, e1, e2, e3);
    }

    const int qiA = qbA + w * 16 + lm;
    const bool maskA = (k0 + 63 > qbA + w * 16);
    #pragma unroll
    for (int n = 0; n < 4; ++n) {
        const int kv0 = k0 + n * 16 + quad * 4;
        float e0, e1, e2, e3;
        if (maskA) {
            e0 = (kv0     > qiA) ? 0.f : __builtin_amdgcn_exp2f(stA[n][0]);
            e1 = (kv0 + 1 > qiA) ? 0.f : __builtin_amdgcn_exp2f(stA[n][1]);
            e2 = (kv0 + 2 > qiA) ? 0.f : __builtin_amdgcn_exp2f(stA[n][2]);
            e3 = (kv0 + 3 > qiA) ? 0.f : __builtin_amdgcn_exp2f(stA[n][3]);
        } else {
            e0 = __builtin_amdgcn_exp2f(stA[n][0]); e1 = __builtin_amdgcn_exp2f(stA[n][1]);
            e2 = __builtin_amdgcn_exp2f(stA[n][2]); e3 = __builtin_amdgcn_exp2f(stA[n][3]);
        }
        lA += (e0 + e1) + (e2 + e3);
        *(bf16x4*)&PtA[lm * PKS + ((n * 4 + quad) ^ ((lm & 7) << 1)) * 4] =
            pk4(e0, e1, e2, e3);
    }

    bf16x8 pB0 = *(const bf16x8*)&PtB[lm * PKS + kb0];
    bf16x8 pB1 = *(const bf16x8*)&PtB[lm * PKS + kb1];
    bf16x8 pA0 = *(const bf16x8*)&PtA[lm * PKS + kb0];
    bf16x8 pA1 = *(const bf16x8*)&PtA[lm * PKS + kb1];
    #pragma unroll
    for (int dt = 0; dt < 4; ++dt) {
        bf16x8 vf0 = *(const bf16x8*)&Vs[(dt * 16 + lm) * RS + kb0];
        bf16x8 vf1 = *(const bf16x8*)&Vs[(dt * 16 + lm) * RS + kb1];
        oB[dt] = mfma16(vf0, pB0, oB[dt]);
        oB[dt] = mfma16(vf1, pB1, oB[dt]);
        oA[dt] = mfma16(vf0, pA0, oA[dt]);
        oA[dt] = mfma16(vf1, pA1, oA[dt]);
    }
}

__device__ inline void attn_epilogue(
    f32x4 (&oacc)[4], float l,
    int qbase, int w, int lm, int quad, int b, int h, __bf16* o)
{
    float ls = l;
    ls += __shfl_xor(ls, 16);
    ls += __shfl_xor(ls, 32);
    float rinv = 1.0f / ls;
    const size_t rowbase = (size_t)(b * 2048 + qbase + w * 16 + lm) * 2048 + h * 64;
    #pragma unroll
    for (int dt = 0; dt < 4; ++dt) {
        *(bf16x4*)(o + rowbase + dt * 16 + quad * 4) =
            pk4(oacc[dt][0] * rinv, oacc[dt][1] * rinv,
                oacc[dt][2] * rinv, oacc[dt][3] * rinv);
    }
}

__global__ __launch_bounds__(512, 4) void attn_kernel(
    const __bf16* __restrict__ qkv, const __bf16* __restrict__ vt,
    __bf16* __restrict__ o)
{
    __shared__ __bf16 Ks[2][64 * RS];
    __shared__ __bf16 Vs[2][64 * RS];
    __shared__ __bf16 Pt[8][2][16 * PKS];
    const int tid  = threadIdx.x;
    const int w    = tid >> 6;
    const int lane = tid & 63;
    const int lm   = lane & 15;
    const int quad = lane >> 4;
    const int p = blockIdx.x, h = blockIdx.y, b = blockIdx.z;
    const int kvh = h >> 2;
    const int qbA = p * 128, qbB = (15 - p) * 128;
    const int ntA = 2 * p + 2, ntB = 32 - 2 * p;
    __bf16* PtwB = &Pt[w][0][0];
    __bf16* PtwA = &Pt[w][1][0];

    bf16x8 qfA[2], qfB[2];
    #pragma unroll
    for (int kh = 0; kh < 2; ++kh) {
        qfA[kh] = *(const bf16x8*)(qkv + (size_t)(b * 2048 + qbA + w * 16 + lm) * 3072
                                      + h * 64 + kh * 32 + quad * 8);
        qfB[kh] = *(const bf16x8*)(qkv + (size_t)(b * 2048 + qbB + w * 16 + lm) * 3072
                                      + h * 64 + kh * 32 + quad * 8);
    }

    f32x4 oA[4], oB[4];
    float lA = 0.f, lB = 0.f;
    #pragma unroll
    for (int j = 0; j < 4; ++j) {
        oA[j] = (f32x4){0.f, 0.f, 0.f, 0.f};
        oB[j] = (f32x4){0.f, 0.f, 0.f, 0.f};
    }

    const int srow = tid >> 3;
    const int scg  = (tid & 7) * 8;                          // global col
    const int scl  = (((tid & 7) ^ (srow & 7))) * 8;         // swizzled LDS col
    const __bf16* kbase = qkv + (size_t)(b * 2048) * 3072 + 2048 + kvh * 64;
    const __bf16* vbase = vt  + (size_t)(kvh * 64 + srow) * 4096 + b * 2048;

    int4 kr0, vr0;
    kr0 = *(const int4*)(kbase + (size_t)srow * 3072 + scg);
    vr0 = *(const int4*)(vbase + scg);

    for (int kt = 0; kt < ntB; ++kt) {
        const int c = kt & 1;
        const int k0 = kt * 64;
        *(int4*)&Ks[c][srow * RS + scl] = kr0;
        *(int4*)&Vs[c][srow * RS + scl] = vr0;
        if (kt + 1 < ntB) {
            kr0 = *(const int4*)(kbase + (size_t)(k0 + 64 + srow) * 3072 + scg);
            vr0 = *(const int4*)(vbase + k0 + 64 + scg);
        }
        __syncthreads();
        if (kt < ntA)
            attn_tile2(qfA, qfB, oA, oB, lA, lB, qbA, k0, w, lm, quad,
                       Ks[c], Vs[c], PtwA, PtwB);
        else
            attn_tile(qfB, oB, lB, qbB, k0, w, lm, quad, Ks[c], Vs[c], PtwB);
    }

    attn_epilogue(oA, lA, qbA, w, lm, quad, b, h, o);
    attn_epilogue(oB, lB, qbB, w, lm, quad, b, h, o);
}

// ---------------------------------------------------------------------------
extern "C" void kernel_launch(void* const* d_in, const int* in_sizes, int n_in,
                              void* d_out, int out_size, void* d_ws, size_t ws_size,
                              hipStream_t stream)
{
    const float* x  = (const float*)d_in[0];
    const float* Wq = (const float*)d_in[1];
    const float* Wk = (const float*)d_in[2];
    const float* Wv = (const float*)d_in[3];
    const float* Wo = (const float*)d_in[4];

    const size_t Mi = 1u << 20;
    // d_out (32 MiB fp32) is scratch until the final GEMM writes it.
    char* ob = (char*)d_out;
    __bf16* xb    = (__bf16*)ob;              // 16 MiB  [4096][2048]
    __bf16* wqkvb = (__bf16*)(ob + 16 * Mi);  // 12 MiB  [3072][2048]
    __bf16* vt    = (__bf16*)(ob + 28 * Mi);  //  4 MiB  [512][4096]
    // d_ws (>= 40 MiB, proven)
    char* ws = (char*)d_ws;
    __bf16* qkvc = (__bf16*)ws;               // 24 MiB  [4096][3072]  Q|K|V
    __bf16* aws  = (__bf16*)(ws + 24 * Mi);   // 16 MiB  [4096][2048]
    __bf16* wob  = (__bf16*)ws;               //  8 MiB, reuses qkvc after attn

    dim3 blk(256);
    cvt4_kernel<<<14336, blk, 0, stream>>>(x, Wq, Wk, Wv, xb, wqkvb);
    gemm256<true, false><<<dim3(12, 16), dim3(512), 0, stream>>>(xb, wqkvb, qkvc, 4096, 3072, 2048);
    transpose_kernel<<<dim3(64, 8), blk, 0, stream>>>(qkvc + 2560, vt, 3072);
    attn_kernel<<<dim3(8, 32, 2), dim3(512), 0, stream>>>(qkvc, vt, aws);
    cvt_kernel<<<4096, blk, 0, stream>>>(Wo, wob, 1048576);
    gemm_o<<<dim3(16, 16), dim3(512), 0, stream>>>(aws, wob, (float*)d_out, 4096, 2048, 2048);
}

// Round 6
// 281.685 us; speedup vs baseline: 1.2301x; 1.0391x over previous
//
#include <hip/hip_runtime.h>

// ---------------------------------------------------------------------------
// GQA forward, fp32 I/O, bf16 MFMA compute.
// B=2 S=2048 D=2048 HQ=32 HKV=8 HD=64.
// cvt4 (w/ head-col permutation for Q,K) -> QKV GEMM (ROUND-10: 256x192
// 4-phase pipelined, grid 16x16 = 256 blocks = 1/CU, counted vmcnt(7), XOR
// swizzle, fused RoPE on permuted pairs, un-permuted C-write) -> V transpose
// -> flash attn (XOR-swizzled LDS, fused paired-tile) -> cvt(Wo) ->
// O GEMM (256x128 4-phase, 256 blocks).
// ---------------------------------------------------------------------------

typedef __bf16 bf16x8 __attribute__((ext_vector_type(8)));
typedef __bf16 bf16x4 __attribute__((ext_vector_type(4)));
typedef float f32x4 __attribute__((ext_vector_type(4)));

__device__ inline f32x4 mfma16(bf16x8 a, bf16x8 b, f32x4 c) {
    return __builtin_amdgcn_mfma_f32_16x16x32_bf16(a, b, c, 0, 0, 0);
}

__device__ inline void gld16(const __bf16* g, __bf16* l) {
    __builtin_amdgcn_global_load_lds(
        (const __attribute__((address_space(1))) void*)g,
        (__attribute__((address_space(3))) void*)l, 16, 0, 0);
}

__device__ inline bf16x4 pk4(float a, float b, float c, float d) {
    bf16x4 r; r[0] = (__bf16)a; r[1] = (__bf16)b; r[2] = (__bf16)c; r[3] = (__bf16)d;
    return r;
}

// 1/sqrt(64) * log2(e): attn computes exp2(score) = exp(qk/8)
#define SCALE_Q 0.18033688011112042f
#define L2IF    0.4152410118609203f    // log2(10000)/32
#define INV2PI  0.15915494309189535f

// Head-column permutation: natural within-head d -> storage slot.
// Storage order per 64-head: (0-15, 32-47, 16-31, 48-63); RoPE pairs (d,d+32)
// land in adjacent 16-col j-blocks.
__device__ inline int permrow(int n) {
    int nod = n & 63;
    int hj = ((nod >> 5) & 1) | (((nod >> 4) & 1) << 1);
    return (n & ~63) | (hj << 4) | (nod & 15);
}

// ---------------- fused fp32->bf16 for x, Wq, Wk, Wv ------------------------
__global__ void cvt4_kernel(const float* __restrict__ x,  const float* __restrict__ wq,
                            const float* __restrict__ wk, const float* __restrict__ wv,
                            __bf16* __restrict__ xb, __bf16* __restrict__ wqkvb)
{
    int i = blockIdx.x * blockDim.x + threadIdx.x;
    const float* src; __bf16* dst;
    if (i < 2097152)      { src = x  + (size_t)i * 4;  dst = xb + (size_t)i * 4; }
    else if (i < 3145728) {
        int j = i - 2097152; int n = j >> 9; int off = (j & 511) * 4;
        src = wq + (size_t)j * 4;
        dst = wqkvb + (size_t)permrow(n) * 2048 + off;
    }
    else if (i < 3407872) {
        int j = i - 3145728; int n = j >> 9; int off = (j & 511) * 4;
        src = wk + (size_t)j * 4;
        dst = wqkvb + 4194304 + (size_t)permrow(n) * 2048 + off;
    }
    else                  { int j = i - 3407872; src = wv + (size_t)j * 4; dst = wqkvb + 5242880 + (size_t)j * 4; }
    float4 f = *(const float4*)src;
    *(bf16x4*)dst = pk4(f.x, f.y, f.z, f.w);
}

__global__ void cvt_kernel(const float* __restrict__ in, __bf16* __restrict__ out, int n4)
{
    int i = blockIdx.x * blockDim.x + threadIdx.x;
    if (i >= n4) return;
    float4 f = ((const float4*)in)[i];
    ((bf16x4*)out)[i] = pk4(f.x, f.y, f.z, f.w);
}

// ---------------- 256x192 4-phase GEMM (QKV): C = A[M,K] * Bw[N,K]^T --------
// 512 thr = 8 waves (4M x 2N), per-wave 64x96 = acc[4][6]. Grid 16x16 = 256
// blocks = exactly 1/CU. K-tile 64; 7 loads/tile (A:4, B:3); vmcnt(7)/tile.
// Bw rows are head-col-permuted for Q/K; C-write un-permutes.
__global__ __launch_bounds__(512, 2) void gemm_qkv(
    const __bf16* __restrict__ A, const __bf16* __restrict__ Bw,
    __bf16* __restrict__ C, int M, int N, int K)
{
    __shared__ __bf16 LA[2][16384];   // 256 x 64
    __shared__ __bf16 LB[2][12288];   // 192 x 64
    const int tid  = threadIdx.x;
    const int lane = tid & 63;
    const int w    = tid >> 6;
    const int lm   = lane & 15;
    const int quad = lane >> 4;
    const int wr   = w >> 1;     // 0..3 (M)
    const int wc   = w & 1;      // 0..1 (N)

    int bx, by;
    {
        int id  = blockIdx.x + gridDim.x * blockIdx.y;   // 256 wgs
        int swz = (id & 7) * 32 + (id >> 3);
        by = swz >> 4;
        bx = swz & 15;
    }
    const int m0 = by * 256;
    const int n0 = bx * 192;
    const int NT = K >> 6;

    const int srow = tid >> 3;
    const int scol = ((tid & 7) ^ (srow & 7)) * 8;   // pre-swizzled source col
    const int ldst = tid * 8;                        // linear LDS dest
    const __bf16* ga = A  + (size_t)(m0 + srow) * K + scol;
    const __bf16* gb = Bw + (size_t)(n0 + srow) * K + scol;

    auto STA = [&](int bf, int r, int u) {
        gld16(ga + (size_t)r * K + u * 64, &LA[bf][r * 64 + ldst]);
    };
    auto STB = [&](int bf, int r, int u) {
        gld16(gb + (size_t)r * K + u * 64, &LB[bf][r * 64 + ldst]);
    };

    f32x4 acc[4][6];
    #pragma unroll
    for (int i = 0; i < 4; ++i)
        #pragma unroll
        for (int j = 0; j < 6; ++j)
            acc[i][j] = (f32x4){0.f, 0.f, 0.f, 0.f};

    const int axo = (wr * 64 + lm) * 64;
    const int bxo = (wc * 96 + lm) * 64;
    const int ks0 = ((quad * 8)      ^ ((lm & 7) * 8));
    const int ks1 = ((32 + quad * 8) ^ ((lm & 7) * 8));

    // prologue: t0 (7) + t1 (7), drain to t0
    STA(0, 0, 0); STA(0, 64, 0); STA(0, 128, 0); STA(0, 192, 0);
    STB(0, 0, 0); STB(0, 64, 0); STB(0, 128, 0);
    STA(1, 0, 1); STA(1, 64, 1); STA(1, 128, 1); STA(1, 192, 1);
    STB(1, 0, 1); STB(1, 64, 1); STB(1, 128, 1);
    asm volatile("s_waitcnt vmcnt(7)" ::: "memory");
    __builtin_amdgcn_s_barrier();
    asm volatile("" ::: "memory");

    bf16x8 Af[2][2], B1[3][2], B2[3][2];
    for (int t = 0; t < NT; ++t) {
        const int b = t & 1;
        const __bf16* la = LA[b];
        const __bf16* lb = LB[b];
        // ---- P1: read A m01 + B n012; MFMA (m01, n012)
        #pragma unroll
        for (int mi = 0; mi < 2; ++mi) {
            Af[mi][0] = *(const bf16x8*)(la + axo + mi * 1024 + ks0);
            Af[mi][1] = *(const bf16x8*)(la + axo + mi * 1024 + ks1);
        }
        #pragma unroll
        for (int ni = 0; ni < 3; ++ni) {
            B1[ni][0] = *(const bf16x8*)(lb + bxo + ni * 1024 + ks0);
            B1[ni][1] = *(const bf16x8*)(lb + bxo + ni * 1024 + ks1);
        }
        __builtin_amdgcn_s_barrier();
        asm volatile("s_waitcnt lgkmcnt(0)" ::: "memory");
        __builtin_amdgcn_s_setprio(1);
        #pragma unroll
        for (int mi = 0; mi < 2; ++mi)
            #pragma unroll
            for (int ni = 0; ni < 3; ++ni) {
                acc[mi][ni] = mfma16(Af[mi][0], B1[ni][0], acc[mi][ni]);
                acc[mi][ni] = mfma16(Af[mi][1], B1[ni][1], acc[mi][ni]);
            }
        __builtin_amdgcn_s_setprio(0);
        __builtin_amdgcn_s_barrier();
        // ---- P2: read B n345; MFMA (m01, n345)
        #pragma unroll
        for (int ni = 0; ni < 3; ++ni) {
            B2[ni][0] = *(const bf16x8*)(lb + bxo + (ni + 3) * 1024 + ks0);
            B2[ni][1] = *(const bf16x8*)(lb + bxo + (ni + 3) * 1024 + ks1);
        }
        __builtin_amdgcn_s_barrier();
        asm volatile("s_waitcnt lgkmcnt(0)" ::: "memory");
        __builtin_amdgcn_s_setprio(1);
        #pragma unroll
        for (int mi = 0; mi < 2; ++mi)
            #pragma unroll
            for (int ni = 0; ni < 3; ++ni) {
                acc[mi][ni + 3] = mfma16(Af[mi][0], B2[ni][0], acc[mi][ni + 3]);
                acc[mi][ni + 3] = mfma16(Af[mi][1], B2[ni][1], acc[mi][ni + 3]);
            }
        __builtin_amdgcn_s_setprio(0);
        __builtin_amdgcn_s_barrier();
        // ---- P3: read A m23; stage B(t+2); MFMA (m23, n012)
        #pragma unroll
        for (int mi = 0; mi < 2; ++mi) {
            Af[mi][0] = *(const bf16x8*)(la + axo + (mi + 2) * 1024 + ks0);
            Af[mi][1] = *(const bf16x8*)(la + axo + (mi + 2) * 1024 + ks1);
        }
        if (t + 2 < NT) { STB(b, 0, t + 2); STB(b, 64, t + 2); STB(b, 128, t + 2); }
        __builtin_amdgcn_s_barrier();
        asm volatile("s_waitcnt lgkmcnt(0)" ::: "memory");
        __builtin_amdgcn_s_setprio(1);
        #pragma unroll
        for (int mi = 0; mi < 2; ++mi)
            #pragma unroll
            for (int ni = 0; ni < 3; ++ni) {
                acc[mi + 2][ni] = mfma16(Af[mi][0], B1[ni][0], acc[mi + 2][ni]);
                acc[mi + 2][ni] = mfma16(Af[mi][1], B1[ni][1], acc[mi + 2][ni]);
            }
        __builtin_amdgcn_s_setprio(0);
        __builtin_amdgcn_s_barrier();
        // ---- P4: stage A(t+2); MFMA (m23, n345); counted vmcnt
        if (t + 2 < NT) {
            STA(b, 0, t + 2); STA(b, 64, t + 2);
            STA(b, 128, t + 2); STA(b, 192, t + 2);
        }
        __builtin_amdgcn_s_setprio(1);
        #pragma unroll
        for (int mi = 0; mi < 2; ++mi)
            #pragma unroll
            for (int ni = 0; ni < 3; ++ni) {
                acc[mi + 2][ni + 3] = mfma16(Af[mi][0], B2[ni][0], acc[mi + 2][ni + 3]);
                acc[mi + 2][ni + 3] = mfma16(Af[mi][1], B2[ni][1], acc[mi + 2][ni + 3]);
            }
        __builtin_amdgcn_s_setprio(0);
        if (t < NT - 2) asm volatile("s_waitcnt vmcnt(7)" ::: "memory");
        else            asm volatile("s_waitcnt vmcnt(0)" ::: "memory");
        __builtin_amdgcn_s_barrier();
        asm volatile("" ::: "memory");
    }

    // RoPE on permuted pairs: pair = (j even, j+1), freq idx = (hj>>1)*16+lm.
    {
        float invr[2];
        invr[0] = exp2f(-(float)lm        * L2IF) * INV2PI;
        invr[1] = exp2f(-(float)(16 + lm) * L2IF) * INV2PI;
        #pragma unroll
        for (int jp = 0; jp < 3; ++jp) {
            const int jlo = jp * 2;
            const int pcb = n0 + wc * 96 + jlo * 16;
            if (pcb >= 2560) continue;                 // V: no rope (wave-uniform)
            const int hj = (pcb >> 4) & 3;             // even
            const float fr = invr[hj >> 1];
            #pragma unroll
            for (int i = 0; i < 4; ++i)
                #pragma unroll
                for (int r = 0; r < 4; ++r) {
                    float tt = (float)((m0 + wr * 64 + i * 16 + quad * 4 + r) & 2047);
                    float aR = tt * fr;
                    aR -= floorf(aR);                  // revolutions
                    float cs = __builtin_amdgcn_cosf(aR);
                    float sn = __builtin_amdgcn_sinf(aR);
                    float x1 = acc[i][jlo][r], x2 = acc[i][jlo + 1][r];
                    acc[i][jlo][r]     = x1 * cs - x2 * sn;
                    acc[i][jlo + 1][r] = x2 * cs + x1 * sn;
                }
        }
    }

    // C-write: un-permute Q/K cols, scale Q.
    #pragma unroll
    for (int j = 0; j < 6; ++j) {
        const int pcb = n0 + wc * 96 + j * 16;
        int colb; float sc;
        if (pcb < 2560) {
            const int hj = (pcb >> 4) & 3;
            colb = (pcb & ~63) | ((hj & 1) << 5) | ((hj >> 1) << 4);
            sc = (pcb < 2048) ? SCALE_Q : 1.0f;
        } else { colb = pcb; sc = 1.0f; }
        #pragma unroll
        for (int i = 0; i < 4; ++i)
            #pragma unroll
            for (int r = 0; r < 4; ++r) {
                int row = m0 + wr * 64 + i * 16 + quad * 4 + r;
                C[(size_t)row * N + colb + lm] = (__bf16)(acc[i][j][r] * sc);
            }
    }
}

// ---------------- 256x128 4-phase GEMM (O proj): C fp32 ---------------------
__global__ __launch_bounds__(512, 2) void gemm_o(
    const __bf16* __restrict__ A, const __bf16* __restrict__ Bw,
    float* __restrict__ C, int M, int N, int K)
{
    __shared__ __bf16 LA[2][16384];   // 256x64
    __shared__ __bf16 LB[2][8192];    // 128x64
    const int tid  = threadIdx.x;
    const int lane = tid & 63;
    const int w    = tid >> 6;
    const int lm   = lane & 15;
    const int quad = lane >> 4;
    const int wr   = w >> 1;     // 0..3
    const int wc   = w & 1;      // 0..1

    int bx, by;
    {
        int id  = blockIdx.x + gridDim.x * blockIdx.y;   // 256 wgs
        int swz = (id & 7) * 32 + (id >> 3);
        by = swz >> 4;
        bx = swz & 15;
    }
    const int m0 = by * 256;
    const int n0 = bx * 128;
    const int NT = K >> 6;

    const int srow = tid >> 3;
    const int scol = ((tid & 7) ^ (srow & 7)) * 8;
    const int ldst = tid * 8;
    const __bf16* ga = A  + (size_t)(m0 + srow) * K + scol;
    const __bf16* gb = Bw + (size_t)(n0 + srow) * K + scol;

    auto STA = [&](int bf, int r, int u) {
        gld16(ga + (size_t)r * K + u * 64, &LA[bf][r * 64 + ldst]);
    };
    auto STB = [&](int bf, int r, int u) {
        gld16(gb + (size_t)r * K + u * 64, &LB[bf][r * 64 + ldst]);
    };

    f32x4 acc[4][4];
    #pragma unroll
    for (int i = 0; i < 4; ++i)
        #pragma unroll
        for (int j = 0; j < 4; ++j)
            acc[i][j] = (f32x4){0.f, 0.f, 0.f, 0.f};

    const int axo = (wr * 64 + lm) * 64;
    const int bxo = (wc * 64 + lm) * 64;
    const int ks0 = ((quad * 8)      ^ ((lm & 7) * 8));
    const int ks1 = ((32 + quad * 8) ^ ((lm & 7) * 8));

    STA(0, 0, 0); STA(0, 64, 0); STA(0, 128, 0); STA(0, 192, 0);
    STB(0, 0, 0); STB(0, 64, 0);
    STA(1, 0, 1); STA(1, 64, 1); STA(1, 128, 1); STA(1, 192, 1);
    STB(1, 0, 1); STB(1, 64, 1);
    asm volatile("s_waitcnt vmcnt(6)" ::: "memory");
    __builtin_amdgcn_s_barrier();
    asm volatile("" ::: "memory");

    bf16x8 Af[4][2], Bf[4][2];
    for (int t = 0; t < NT; ++t) {
        const int b = t & 1;
        const __bf16* la = LA[b];
        const __bf16* lb = LB[b];
        #pragma unroll
        for (int mi = 0; mi < 2; ++mi) {
            Af[mi][0] = *(const bf16x8*)(la + axo + mi * 1024 + ks0);
            Af[mi][1] = *(const bf16x8*)(la + axo + mi * 1024 + ks1);
        }
        #pragma unroll
        for (int ni = 0; ni < 2; ++ni) {
            Bf[ni][0] = *(const bf16x8*)(lb + bxo + ni * 1024 + ks0);
            Bf[ni][1] = *(const bf16x8*)(lb + bxo + ni * 1024 + ks1);
        }
        __builtin_amdgcn_s_barrier();
        asm volatile("s_waitcnt lgkmcnt(0)" ::: "memory");
        __builtin_amdgcn_s_setprio(1);
        #pragma unroll
        for (int mi = 0; mi < 2; ++mi)
            #pragma unroll
            for (int ni = 0; ni < 2; ++ni) {
                acc[mi][ni] = mfma16(Af[mi][0], Bf[ni][0], acc[mi][ni]);
                acc[mi][ni] = mfma16(Af[mi][1], Bf[ni][1], acc[mi][ni]);
            }
        __builtin_amdgcn_s_setprio(0);
        __builtin_amdgcn_s_barrier();
        #pragma unroll
        for (int ni = 2; ni < 4; ++ni) {
            Bf[ni][0] = *(const bf16x8*)(lb + bxo + ni * 1024 + ks0);
            Bf[ni][1] = *(const bf16x8*)(lb + bxo + ni * 1024 + ks1);
        }
        __builtin_amdgcn_s_barrier();
        asm volatile("s_waitcnt lgkmcnt(0)" ::: "memory");
        __builtin_amdgcn_s_setprio(1);
        #pragma unroll
        for (int mi = 0; mi < 2; ++mi)
            #pragma unroll
            for (int ni = 2; ni < 4; ++ni) {
                acc[mi][ni] = mfma16(Af[mi][0], Bf[ni][0], acc[mi][ni]);
                acc[mi][ni] = mfma16(Af[mi][1], Bf[ni][1], acc[mi][ni]);
            }
        __builtin_amdgcn_s_setprio(0);
        __builtin_amdgcn_s_barrier();
        #pragma unroll
        for (int mi = 2; mi < 4; ++mi) {
            Af[mi][0] = *(const bf16x8*)(la + axo + mi * 1024 + ks0);
            Af[mi][1] = *(const bf16x8*)(la + axo + mi * 1024 + ks1);
        }
        if (t + 2 < NT) { STB(b, 0, t + 2); STB(b, 64, t + 2); }
        __builtin_amdgcn_s_barrier();
        asm volatile("s_waitcnt lgkmcnt(0)" ::: "memory");
        __builtin_amdgcn_s_setprio(1);
        #pragma unroll
        for (int mi = 2; mi < 4; ++mi)
            #pragma unroll
            for (int ni = 0; ni < 2; ++ni) {
                acc[mi][ni] = mfma16(Af[mi][0], Bf[ni][0], acc[mi][ni]);
                acc[mi][ni] = mfma16(Af[mi][1], Bf[ni][1], acc[mi][ni]);
            }
        __builtin_amdgcn_s_setprio(0);
        __builtin_amdgcn_s_barrier();
        if (t + 2 < NT) {
            STA(b, 0, t + 2); STA(b, 64, t + 2);
            STA(b, 128, t + 2); STA(b, 192, t + 2);
        }
        __builtin_amdgcn_s_setprio(1);
        #pragma unroll
        for (int mi = 2; mi < 4; ++mi)
            #pragma unroll
            for (int ni = 2; ni < 4; ++ni) {
                acc[mi][ni] = mfma16(Af[mi][0], Bf[ni][0], acc[mi][ni]);
                acc[mi][ni] = mfma16(Af[mi][1], Bf[ni][1], acc[mi][ni]);
            }
        __builtin_amdgcn_s_setprio(0);
        if (t < NT - 2) asm volatile("s_waitcnt vmcnt(6)" ::: "memory");
        else            asm volatile("s_waitcnt vmcnt(0)" ::: "memory");
        __builtin_amdgcn_s_barrier();
        asm volatile("" ::: "memory");
    }

    #pragma unroll
    for (int i = 0; i < 4; ++i)
        #pragma unroll
        for (int j = 0; j < 4; ++j)
            #pragma unroll
            for (int r = 0; r < 4; ++r) {
                int row = m0 + wr * 64 + i * 16 + quad * 4 + r;
                int col = n0 + wc * 64 + j * 16 + lm;
                C[(size_t)row * N + col] = acc[i][j][r];
            }
}

// ---------------- V transpose: [4096 tok][512 d] (stride 3072) -> [512][4096]
__global__ __launch_bounds__(256) void transpose_kernel(
    const __bf16* __restrict__ in, __bf16* __restrict__ out, int rowstride)
{
    __shared__ __bf16 T[64][72];
    const int t0 = blockIdx.x * 64;
    const int d0 = blockIdx.y * 64;
    const int r = threadIdx.x >> 2, c = (threadIdx.x & 3) * 16;
    *(int4*)&T[r][c]     = *(const int4*)(in + (size_t)(t0 + r) * rowstride + d0 + c);
    *(int4*)&T[r][c + 8] = *(const int4*)(in + (size_t)(t0 + r) * rowstride + d0 + c + 8);
    __syncthreads();
    bf16x8 o0, o1;
    #pragma unroll
    for (int i = 0; i < 8; ++i) { o0[i] = T[c + i][r]; o1[i] = T[c + 8 + i][r]; }
    *(bf16x8*)(out + (size_t)(d0 + r) * 4096 + t0 + c)     = o0;
    *(bf16x8*)(out + (size_t)(d0 + r) * 4096 + t0 + c + 8) = o1;
}

// ---------------- Flash attention (XOR-swizzled LDS, fused paired tiles) ----
#define RS  64
#define PKS 64

__device__ inline void attn_tile(
    const bf16x8 (&qf)[2], f32x4 (&oacc)[4], float& l,
    int qbase, int k0, int w, int lm, int quad,
    const __bf16* Ks, const __bf16* Vs, __bf16* Ptw)
{
    const int kb0 = (quad ^ (lm & 7)) * 8;
    const int kb1 = ((quad + 4) ^ (lm & 7)) * 8;
    f32x4 st[4];
    #pragma unroll
    for (int n = 0; n < 4; ++n)
        st[n] = (f32x4){0.f, 0.f, 0.f, 0.f};

    #pragma unroll
    for (int n = 0; n < 4; ++n) {
        bf16x8 kf0 = *(const bf16x8*)&Ks[(n * 16 + lm) * RS + kb0];
        bf16x8 kf1 = *(const bf16x8*)&Ks[(n * 16 + lm) * RS + kb1];
        st[n] = mfma16(kf0, qf[0], st[n]);
        st[n] = mfma16(kf1, qf[1], st[n]);
    }

    const int qi = qbase + w * 16 + lm;
    const bool any_mask = (k0 + 63 > qbase + w * 16);
    #pragma unroll
    for (int n = 0; n < 4; ++n) {
        const int kv0 = k0 + n * 16 + quad * 4;
        float e0, e1, e2, e3;
        if (any_mask) {
            e0 = (kv0     > qi) ? 0.f : __builtin_amdgcn_exp2f(st[n][0]);
            e1 = (kv0 + 1 > qi) ? 0.f : __builtin_amdgcn_exp2f(st[n][1]);
            e2 = (kv0 + 2 > qi) ? 0.f : __builtin_amdgcn_exp2f(st[n][2]);
            e3 = (kv0 + 3 > qi) ? 0.f : __builtin_amdgcn_exp2f(st[n][3]);
        } else {
            e0 = __builtin_amdgcn_exp2f(st[n][0]); e1 = __builtin_amdgcn_exp2f(st[n][1]);
            e2 = __builtin_amdgcn_exp2f(st[n][2]); e3 = __builtin_amdgcn_exp2f(st[n][3]);
        }
        l += (e0 + e1) + (e2 + e3);
        *(bf16x4*)&Ptw[lm * PKS + ((n * 4 + quad) ^ ((lm & 7) << 1)) * 4] =
            pk4(e0, e1, e2, e3);
    }

    bf16x8 pf0 = *(const bf16x8*)&Ptw[lm * PKS + kb0];
    bf16x8 pf1 = *(const bf16x8*)&Ptw[lm * PKS + kb1];
    #pragma unroll
    for (int dt = 0; dt < 4; ++dt) {
        bf16x8 vf0 = *(const bf16x8*)&Vs[(dt * 16 + lm) * RS + kb0];
        bf16x8 vf1 = *(const bf16x8*)&Vs[(dt * 16 + lm) * RS + kb1];
        oacc[dt] = mfma16(vf0, pf0, oacc[dt]);
        oacc[dt] = mfma16(vf1, pf1, oacc[dt]);
    }
}

__device__ inline void attn_tile2(
    const bf16x8 (&qfA)[2], const bf16x8 (&qfB)[2],
    f32x4 (&oA)[4], f32x4 (&oB)[4], float& lA, float& lB,
    int qbA, int k0, int w, int lm, int quad,
    const __bf16* Ks, const __bf16* Vs, __bf16* PtA, __bf16* PtB)
{
    const int kb0 = (quad ^ (lm & 7)) * 8;
    const int kb1 = ((quad + 4) ^ (lm & 7)) * 8;
    f32x4 stA[4], stB[4];
    #pragma unroll
    for (int n = 0; n < 4; ++n) {
        stA[n] = (f32x4){0.f, 0.f, 0.f, 0.f};
        stB[n] = (f32x4){0.f, 0.f, 0.f, 0.f};
    }

    #pragma unroll
    for (int n = 0; n < 4; ++n) {
        bf16x8 kf0 = *(const bf16x8*)&Ks[(n * 16 + lm) * RS + kb0];
        bf16x8 kf1 = *(const bf16x8*)&Ks[(n * 16 + lm) * RS + kb1];
        stB[n] = mfma16(kf0, qfB[0], stB[n]);
        stB[n] = mfma16(kf1, qfB[1], stB[n]);
        stA[n] = mfma16(kf0, qfA[0], stA[n]);
        stA[n] = mfma16(kf1, qfA[1], stA[n]);
    }

    #pragma unroll
    for (int n = 0; n < 4; ++n) {
        float e0 = __builtin_amdgcn_exp2f(stB[n][0]);
        float e1 = __builtin_amdgcn_exp2f(stB[n][1]);
        float e2 = __builtin_amdgcn_exp2f(stB[n][2]);
        float e3 = __builtin_amdgcn_exp2f(stB[n][3]);
        lB += (e0 + e1) + (e2 + e3);
        *(bf16x4*)&PtB[lm * PKS + ((n * 4 + quad) ^ ((lm & 7) << 1)) * 4] =
            pk4(e0, e1, e2, e3);
    }

    const int qiA = qbA + w * 16 + lm;
    const bool maskA = (k0 + 63 > qbA + w * 16);
    #pragma unroll
    for (int n = 0; n < 4; ++n) {
        const int kv0 = k0 + n * 16 + quad * 4;
        float e0, e1, e2, e3;
        if (maskA) {
            e0 = (kv0     > qiA) ? 0.f : __builtin_amdgcn_exp2f(stA[n][0]);
            e1 = (kv0 + 1 > qiA) ? 0.f : __builtin_amdgcn_exp2f(stA[n][1]);
            e2 = (kv0 + 2 > qiA) ? 0.f : __builtin_amdgcn_exp2f(stA[n][2]);
            e3 = (kv0 + 3 > qiA) ? 0.f : __builtin_amdgcn_exp2f(stA[n][3]);
        } else {
            e0 = __builtin_amdgcn_exp2f(stA[n][0]); e1 = __builtin_amdgcn_exp2f(stA[n][1]);
            e2 = __builtin_amdgcn_exp2f(stA[n][2]); e3 = __builtin_amdgcn_exp2f(stA[n][3]);
        }
        lA += (e0 + e1) + (e2 + e3);
        *(bf16x4*)&PtA[lm * PKS + ((n * 4 + quad) ^ ((lm & 7) << 1)) * 4] =
            pk4(e0, e1, e2, e3);
    }

    bf16x8 pB0 = *(const bf16x8*)&PtB[lm * PKS + kb0];
    bf16x8 pB1 = *(const bf16x8*)&PtB[lm * PKS + kb1];
    bf16x8 pA0 = *(const bf16x8*)&PtA[lm * PKS + kb0];
    bf16x8 pA1 = *(const bf16x8*)&PtA[lm * PKS + kb1];
    #pragma unroll
    for (int dt = 0; dt < 4; ++dt) {
        bf16x8 vf0 = *(const bf16x8*)&Vs[(dt * 16 + lm) * RS + kb0];
        bf16x8 vf1 = *(const bf16x8*)&Vs[(dt * 16 + lm) * RS + kb1];
        oB[dt] = mfma16(vf0, pB0, oB[dt]);
        oB[dt] = mfma16(vf1, pB1, oB[dt]);
        oA[dt] = mfma16(vf0, pA0, oA[dt]);
        oA[dt] = mfma16(vf1, pA1, oA[dt]);
    }
}

__device__ inline void attn_epilogue(
    f32x4 (&oacc)[4], float l,
    int qbase, int w, int lm, int quad, int b, int h, __bf16* o)
{
    float ls = l;
    ls += __shfl_xor(ls, 16);
    ls += __shfl_xor(ls, 32);
    float rinv = 1.0f / ls;
    const size_t rowbase = (size_t)(b * 2048 + qbase + w * 16 + lm) * 2048 + h * 64;
    #pragma unroll
    for (int dt = 0; dt < 4; ++dt) {
        *(bf16x4*)(o + rowbase + dt * 16 + quad * 4) =
            pk4(oacc[dt][0] * rinv, oacc[dt][1] * rinv,
                oacc[dt][2] * rinv, oacc[dt][3] * rinv);
    }
}

__global__ __launch_bounds__(512, 4) void attn_kernel(
    const __bf16* __restrict__ qkv, const __bf16* __restrict__ vt,
    __bf16* __restrict__ o)
{
    __shared__ __bf16 Ks[2][64 * RS];
    __shared__ __bf16 Vs[2][64 * RS];
    __shared__ __bf16 Pt[8][2][16 * PKS];
    const int tid  = threadIdx.x;
    const int w    = tid >> 6;
    const int lane = tid & 63;
    const int lm   = lane & 15;
    const int quad = lane >> 4;
    const int p = blockIdx.x, h = blockIdx.y, b = blockIdx.z;
    const int kvh = h >> 2;
    const int qbA = p * 128, qbB = (15 - p) * 128;
    const int ntA = 2 * p + 2, ntB = 32 - 2 * p;
    __bf16* PtwB = &Pt[w][0][0];
    __bf16* PtwA = &Pt[w][1][0];

    bf16x8 qfA[2], qfB[2];
    #pragma unroll
    for (int kh = 0; kh < 2; ++kh) {
        qfA[kh] = *(const bf16x8*)(qkv + (size_t)(b * 2048 + qbA + w * 16 + lm) * 3072
                                      + h * 64 + kh * 32 + quad * 8);
        qfB[kh] = *(const bf16x8*)(qkv + (size_t)(b * 2048 + qbB + w * 16 + lm) * 3072
                                      + h * 64 + kh * 32 + quad * 8);
    }

    f32x4 oA[4], oB[4];
    float lA = 0.f, lB = 0.f;
    #pragma unroll
    for (int j = 0; j < 4; ++j) {
        oA[j] = (f32x4){0.f, 0.f, 0.f, 0.f};
        oB[j] = (f32x4){0.f, 0.f, 0.f, 0.f};
    }

    const int srow = tid >> 3;
    const int scg  = (tid & 7) * 8;                          // global col
    const int scl  = (((tid & 7) ^ (srow & 7))) * 8;         // swizzled LDS col
    const __bf16* kbase = qkv + (size_t)(b * 2048) * 3072 + 2048 + kvh * 64;
    const __bf16* vbase = vt  + (size_t)(kvh * 64 + srow) * 4096 + b * 2048;

    int4 kr0, vr0;
    kr0 = *(const int4*)(kbase + (size_t)srow * 3072 + scg);
    vr0 = *(const int4*)(vbase + scg);

    for (int kt = 0; kt < ntB; ++kt) {
        const int c = kt & 1;
        const int k0 = kt * 64;
        *(int4*)&Ks[c][srow * RS + scl] = kr0;
        *(int4*)&Vs[c][srow * RS + scl] = vr0;
        if (kt + 1 < ntB) {
            kr0 = *(const int4*)(kbase + (size_t)(k0 + 64 + srow) * 3072 + scg);
            vr0 = *(const int4*)(vbase + k0 + 64 + scg);
        }
        __syncthreads();
        if (kt < ntA)
            attn_tile2(qfA, qfB, oA, oB, lA, lB, qbA, k0, w, lm, quad,
                       Ks[c], Vs[c], PtwA, PtwB);
        else
            attn_tile(qfB, oB, lB, qbB, k0, w, lm, quad, Ks[c], Vs[c], PtwB);
    }

    attn_epilogue(oA, lA, qbA, w, lm, quad, b, h, o);
    attn_epilogue(oB, lB, qbB, w, lm, quad, b, h, o);
}

// ---------------------------------------------------------------------------
extern "C" void kernel_launch(void* const* d_in, const int* in_sizes, int n_in,
                              void* d_out, int out_size, void* d_ws, size_t ws_size,
                              hipStream_t stream)
{
    const float* x  = (const float*)d_in[0];
    const float* Wq = (const float*)d_in[1];
    const float* Wk = (const float*)d_in[2];
    const float* Wv = (const float*)d_in[3];
    const float* Wo = (const float*)d_in[4];

    const size_t Mi = 1u << 20;
    // d_out (32 MiB fp32) is scratch until the final GEMM writes it.
    char* ob = (char*)d_out;
    __bf16* xb    = (__bf16*)ob;              // 16 MiB  [4096][2048]
    __bf16* wqkvb = (__bf16*)(ob + 16 * Mi);  // 12 MiB  [3072][2048]
    __bf16* vt    = (__bf16*)(ob + 28 * Mi);  //  4 MiB  [512][4096]
    // d_ws (>= 40 MiB, proven)
    char* ws = (char*)d_ws;
    __bf16* qkvc = (__bf16*)ws;               // 24 MiB  [4096][3072]  Q|K|V
    __bf16* aws  = (__bf16*)(ws + 24 * Mi);   // 16 MiB  [4096][2048]
    __bf16* wob  = (__bf16*)ws;               //  8 MiB, reuses qkvc after attn

    dim3 blk(256);
    cvt4_kernel<<<14336, blk, 0, stream>>>(x, Wq, Wk, Wv, xb, wqkvb);
    gemm_qkv<<<dim3(16, 16), dim3(512), 0, stream>>>(xb, wqkvb, qkvc, 4096, 3072, 2048);
    transpose_kernel<<<dim3(64, 8), blk, 0, stream>>>(qkvc + 2560, vt, 3072);
    attn_kernel<<<dim3(8, 32, 2), dim3(512), 0, stream>>>(qkvc, vt, aws);
    cvt_kernel<<<4096, blk, 0, stream>>>(Wo, wob, 1048576);
    gemm_o<<<dim3(16, 16), dim3(512), 0, stream>>>(aws, wob, (float*)d_out, 4096, 2048, 2048);
}